// Round 25
// baseline (711.676 us; speedup 1.0000x reference)
//
#include <hip/hip_runtime.h>
#include <hip/hip_bf16.h>
#include <stdint.h>

#define B_  4
#define T_  1024
#define D_  1024
#define H_  16
#define DH  64
#define F_  4096
#define E_  8
#define NT  (B_*T_)          // 4096 tokens

typedef float f32x4 __attribute__((ext_vector_type(4)));
typedef short bf16x8 __attribute__((ext_vector_type(8)));
#define MFMA_BF16 __builtin_amdgcn_mfma_f32_16x16x32_bf16

union PK8 { uint32_t u[4]; bf16x8 v; };

// ---- bf16 helpers: RNE round, split f32 -> hi/lo bf16 ----
static __device__ __forceinline__ uint16_t f2bf(float f) {
  uint32_t u = __float_as_uint(f);
  u += 0x7FFFu + ((u >> 16) & 1u);
  return (uint16_t)(u >> 16);
}
// unpack 8 packed u32 -> hi / lo bf16x8 (used only for P tiles in fattn)
static __device__ __forceinline__ void unpack8(const uint4 p0, const uint4 p1, bf16x8 &hi, bf16x8 &lo) {
  PK8 H, L;
  H.u[0] = __builtin_amdgcn_perm(p0.y, p0.x, 0x07060302u);
  L.u[0] = __builtin_amdgcn_perm(p0.y, p0.x, 0x05040100u);
  H.u[1] = __builtin_amdgcn_perm(p0.w, p0.z, 0x07060302u);
  L.u[1] = __builtin_amdgcn_perm(p0.w, p0.z, 0x05040100u);
  H.u[2] = __builtin_amdgcn_perm(p1.y, p1.x, 0x07060302u);
  L.u[2] = __builtin_amdgcn_perm(p1.y, p1.x, 0x05040100u);
  H.u[3] = __builtin_amdgcn_perm(p1.w, p1.z, 0x07060302u);
  L.u[3] = __builtin_amdgcn_perm(p1.w, p1.z, 0x05040100u);
  hi = H.v; lo = L.v;
}

// ---------------- merged dense-weight prep: transpose [K=1024][N] -> [N][1024] hi/lo planes ----------------
__global__ __launch_bounds__(256) void k_pack_all(
    const float* __restrict__ wqkv, const float* __restrict__ saw,
    const float* __restrict__ wq,   const float* __restrict__ caw,
    uint16_t* __restrict__ qkvTh, uint16_t* __restrict__ qkvTl,
    uint16_t* __restrict__ sawTh, uint16_t* __restrict__ sawTl,
    uint16_t* __restrict__ wqTh,  uint16_t* __restrict__ wqTl,
    uint16_t* __restrict__ cawTh, uint16_t* __restrict__ cawTl) {
  __shared__ float t[32][33];
  int z = blockIdx.z;
  const float* in; uint16_t *oh, *ol; int N, nbase;
  if (z < 3)       { in = wqkv; oh = qkvTh; ol = qkvTl; N = 3072; nbase = z * 1024; }
  else if (z == 3) { in = saw;  oh = sawTh; ol = sawTl; N = 1024; nbase = 0; }
  else if (z == 4) { in = wq;   oh = wqTh;  ol = wqTl;  N = 1024; nbase = 0; }
  else             { in = caw;  oh = cawTh; ol = cawTl; N = 1024; nbase = 0; }
  int n0 = nbase + blockIdx.x * 32, k0 = blockIdx.y * 32;
  int tx = threadIdx.x & 31, ty = threadIdx.x >> 5;
#pragma unroll
  for (int i = 0; i < 32; i += 8) t[ty + i][tx] = in[(size_t)(k0 + ty + i) * N + n0 + tx];
  __syncthreads();
#pragma unroll
  for (int i = 0; i < 32; i += 8) {
    float v = t[tx][ty + i];
    uint16_t h = f2bf(v);
    uint16_t l = f2bf(v - __uint_as_float((uint32_t)h << 16));
    size_t o = (size_t)(n0 + ty + i) * 1024 + k0 + tx;
    oh[o] = h; ol[o] = l;
  }
}

// merged MoE weight prep: w1 [D][F] and w2 [F][D] -> transposed bf16; z = which*8 + e
__global__ __launch_bounds__(256) void k_bf_t2(const float* __restrict__ w1, const float* __restrict__ w2,
                                               uint16_t* __restrict__ w1t, uint16_t* __restrict__ w2t) {
  __shared__ float t[64][65];
  int z = blockIdx.z;
  int which = z >> 3, e = z & 7;
  const float* in = which ? w2 : w1;
  uint16_t* out = which ? w2t : w1t;
  int K = which ? F_ : D_, N = which ? D_ : F_;
  const size_t mo = (size_t)e * (size_t)D_ * F_;
  in += mo; out += mo;
  int tile = blockIdx.x;
  int n0, k0;
  if (which) { n0 = (tile & 15) * 64; k0 = (tile >> 4) * 64; }
  else       { n0 = (tile & 63) * 64; k0 = (tile >> 6) * 64; }
  int tr = threadIdx.x >> 4;
  int tc = (threadIdx.x & 15) * 4;
#pragma unroll
  for (int i = 0; i < 64; i += 16) {
    float4 v = *(const float4*)&in[(size_t)(k0 + tr + i) * N + n0 + tc];
    t[tr + i][tc] = v.x; t[tr + i][tc + 1] = v.y; t[tr + i][tc + 2] = v.z; t[tr + i][tc + 3] = v.w;
  }
  __syncthreads();
#pragma unroll
  for (int i = 0; i < 64; i += 16) {
    int n = tr + i;
    uint16_t b0 = f2bf(t[tc][n]), b1 = f2bf(t[tc + 1][n]);
    uint16_t b2 = f2bf(t[tc + 2][n]), b3 = f2bf(t[tc + 3][n]);
    uint2 wv;
    wv.x = ((uint32_t)b1 << 16) | b0;
    wv.y = ((uint32_t)b3 << 16) | b2;
    *(uint2*)&out[(size_t)(n0 + n) * K + k0 + tc] = wv;
  }
}

// u16 plane transpose of v-region of qkv planes: [b][t][2048+c] -> vt[(b*1024+c)][t]
__global__ __launch_bounds__(256) void k_t16(const uint16_t* __restrict__ inh, const uint16_t* __restrict__ inl,
                                             uint16_t* __restrict__ outh, uint16_t* __restrict__ outl) {
  __shared__ uint16_t th[64][68], tl[64][68];
  int b = blockIdx.z, t0 = blockIdx.x * 64, c0 = blockIdx.y * 64;
  int tr = threadIdx.x >> 4;
  int tc = (threadIdx.x & 15) * 4;
#pragma unroll
  for (int i = 0; i < 64; i += 16) {
    size_t src = (size_t)(b * T_ + t0 + tr + i) * 3072 + 2048 + c0 + tc;
    *(uint2*)&th[tr + i][tc] = *(const uint2*)&inh[src];
    *(uint2*)&tl[tr + i][tc] = *(const uint2*)&inl[src];
  }
  __syncthreads();
#pragma unroll
  for (int i = 0; i < 64; i += 16) {
    int n = tr + i;
    size_t dst = (size_t)(b * 1024 + c0 + n) * T_ + t0 + tc;
    uint2 ph, pl;
    ph.x = ((uint32_t)th[tc + 1][n] << 16) | th[tc][n];
    ph.y = ((uint32_t)th[tc + 3][n] << 16) | th[tc + 2][n];
    pl.x = ((uint32_t)tl[tc + 1][n] << 16) | tl[tc][n];
    pl.y = ((uint32_t)tl[tc + 3][n] << 16) | tl[tc + 2][n];
    *(uint2*)&outh[dst] = ph;
    *(uint2*)&outl[dst] = pl;
  }
}

// elementwise split f32 -> hi/lo planes
__global__ __launch_bounds__(256) void k_packf2(const float* __restrict__ in,
                                                uint16_t* __restrict__ oh, uint16_t* __restrict__ ol) {
  int i = (blockIdx.x * 256 + threadIdx.x) * 4;
  float4 v = *(const float4*)&in[i];
  uint16_t h0 = f2bf(v.x), h1 = f2bf(v.y), h2 = f2bf(v.z), h3 = f2bf(v.w);
  uint2 ph, pl;
  ph.x = ((uint32_t)h1 << 16) | h0;
  ph.y = ((uint32_t)h3 << 16) | h2;
  pl.x = ((uint32_t)f2bf(v.y - __uint_as_float((uint32_t)h1 << 16)) << 16) |
         f2bf(v.x - __uint_as_float((uint32_t)h0 << 16));
  pl.y = ((uint32_t)f2bf(v.w - __uint_as_float((uint32_t)h3 << 16)) << 16) |
         f2bf(v.z - __uint_as_float((uint32_t)h2 << 16));
  *(uint2*)&oh[i] = ph;
  *(uint2*)&ol[i] = pl;
}

// transpose+split: v_ctx f32 [b][t][gc] (gc<256) -> planes [(b*256+gc)][t]
__global__ __launch_bounds__(256) void k_tf32(const float* __restrict__ in,
                                              uint16_t* __restrict__ oh, uint16_t* __restrict__ ol) {
  __shared__ float t[32][33];
  int b = blockIdx.z, t0 = blockIdx.x * 32, c0 = blockIdx.y * 32;
  int tx = threadIdx.x & 31, ty = threadIdx.x >> 5;
#pragma unroll
  for (int i = 0; i < 32; i += 8)
    t[ty + i][tx] = in[(size_t)(b * T_ + t0 + ty + i) * 256 + c0 + tx];
  __syncthreads();
#pragma unroll
  for (int i = 0; i < 32; i += 8) {
    float v = t[tx][ty + i];
    uint16_t h = f2bf(v);
    size_t o = (size_t)(b * 256 + c0 + ty + i) * T_ + t0 + tx;
    oh[o] = h;
    ol[o] = f2bf(v - __uint_as_float((uint32_t)h << 16));
  }
}

// ---------------- RMSNorm (fp32 exact): hi/lo planes; optional fused MoE gate ----------------
__global__ __launch_bounds__(256) void k_rms(const float* __restrict__ x, const float* __restrict__ w,
                                             uint16_t* __restrict__ oh, uint16_t* __restrict__ ol,
                                             const float* __restrict__ wg, int* __restrict__ idxp,
                                             float* __restrict__ scb) {
  int row = blockIdx.x;
  const float* xr = x + (size_t)row * D_;
  int t = threadIdx.x;
  float4 xv = *(const float4*)&xr[t * 4];
  float s = xv.x * xv.x + xv.y * xv.y + xv.z * xv.z + xv.w * xv.w;
#pragma unroll
  for (int o = 32; o; o >>= 1) s += __shfl_xor(s, o, 64);
  __shared__ float ps[4];
  __shared__ float ga[4][8];
  if ((t & 63) == 0) ps[t >> 6] = s;
  __syncthreads();
  s = ps[0] + ps[1] + ps[2] + ps[3];
  float sc = 1.0f / sqrtf(s * (1.0f / (float)D_) + 1e-6f);
  float4 wv = *(const float4*)&w[t * 4];
  float o0 = xv.x * sc * wv.x, o1 = xv.y * sc * wv.y, o2 = xv.z * sc * wv.z, o3 = xv.w * sc * wv.w;
  uint16_t h0 = f2bf(o0), h1 = f2bf(o1), h2 = f2bf(o2), h3 = f2bf(o3);
  if (oh) {
    uint2 ph;
    ph.x = ((uint32_t)h1 << 16) | h0;
    ph.y = ((uint32_t)h3 << 16) | h2;
    *(uint2*)&oh[(size_t)row * D_ + t * 4] = ph;
  }
  if (ol) {
    uint16_t l0 = f2bf(o0 - __uint_as_float((uint32_t)h0 << 16));
    uint16_t l1 = f2bf(o1 - __uint_as_float((uint32_t)h1 << 16));
    uint16_t l2 = f2bf(o2 - __uint_as_float((uint32_t)h2 << 16));
    uint16_t l3 = f2bf(o3 - __uint_as_float((uint32_t)h3 << 16));
    uint2 pl;
    pl.x = ((uint32_t)l1 << 16) | l0;
    pl.y = ((uint32_t)l3 << 16) | l2;
    *(uint2*)&ol[(size_t)row * D_ + t * 4] = pl;
  }
  if (wg) {
    float a[8] = {};
    float ov[4] = {o0, o1, o2, o3};
#pragma unroll
    for (int j = 0; j < 4; j++) {
      const float* wr = &wg[(size_t)(t * 4 + j) * 8];
      float4 wa = *(const float4*)wr, wb = *(const float4*)(wr + 4);
      float v = ov[j];
      a[0] += v * wa.x; a[1] += v * wa.y; a[2] += v * wa.z; a[3] += v * wa.w;
      a[4] += v * wb.x; a[5] += v * wb.y; a[6] += v * wb.z; a[7] += v * wb.w;
    }
#pragma unroll
    for (int e = 0; e < 8; e++)
#pragma unroll
      for (int o = 32; o; o >>= 1) a[e] += __shfl_xor(a[e], o, 64);
    if ((t & 63) == 0)
#pragma unroll
      for (int e = 0; e < 8; e++) ga[t >> 6][e] = a[e];
    __syncthreads();
    if (t == 0) {
      float g[8];
#pragma unroll
      for (int e = 0; e < 8; e++) g[e] = ga[0][e] + ga[1][e] + ga[2][e] + ga[3][e];
      int bi = 0; float bv = g[0];
#pragma unroll
      for (int e = 1; e < 8; e++) if (g[e] > bv) { bv = g[e]; bi = e; }
      float se = 0.f;
#pragma unroll
      for (int e = 0; e < 8; e++) se += expf(g[e] - bv);
      idxp[row] = bi;
      scb[row] = 1.0f / se;
    }
  }
}

// ---------------- split-bf16 GEMM v13: 128x128 register-blocked tile (fm=fn=4), 3-MFMA split ----------------
// 4 waves in 2x2; per wave per 32-K step: 16 ds_read_b128 -> 48 MFMA (ratio 3.0 vs v10's 2.0).
// LDS image: slot cs of row r holds global 16B-chunk cs ^ (r&3); conflict-free fixed-slot writes (v11).
#define GBM 128
#define GBN 128
__global__ __launch_bounds__(256) void k_gemm_split(const uint16_t* __restrict__ Ahg, const uint16_t* __restrict__ Alg,
                                                    const uint16_t* __restrict__ Whg, const uint16_t* __restrict__ Wlg,
                                                    float* __restrict__ C, const float* __restrict__ res,
                                                    uint16_t* __restrict__ Cph, uint16_t* __restrict__ Cpl,
                                                    int scale_cols, int M, int N, int K) {
  __shared__ uint16_t Ah[GBM][32], Al[GBM][32];
  __shared__ uint16_t Wh[GBN][32], Wl[GBN][32];
  int m0 = blockIdx.y * GBM, n0 = blockIdx.x * GBN;
  int tid = threadIdx.x, wv = tid >> 6, ln = tid & 63, mi = ln & 15, b8 = ln >> 4;
  const int wr = wv >> 1, wc = wv & 1;   // 2x2 wave grid, each wave 64x64 output
  // staging: 2 thr/row (128 rows), fixed LDS slots cs0/cs1, swizzled global source (all 4 arrays)
  int ra = tid >> 1, qa = tid & 1;
  const int cs0 = qa * 2 + ((ra >> 1) & 1);
  const int cs1 = cs0 ^ 1;
  const int sa0 = cs0 * 8;
  const int sa1 = cs1 * 8;
  const int go0 = (cs0 ^ (ra & 3)) * 8;
  const int go1 = (cs1 ^ (ra & 3)) * 8;
  const uint16_t* pAh0 = Ahg + (size_t)(m0 + ra) * K + go0;
  const uint16_t* pAh1 = Ahg + (size_t)(m0 + ra) * K + go1;
  const uint16_t* pAl0 = Alg + (size_t)(m0 + ra) * K + go0;
  const uint16_t* pAl1 = Alg + (size_t)(m0 + ra) * K + go1;
  const uint16_t* pWh0 = Whg + (size_t)(n0 + ra) * K + go0;
  const uint16_t* pWh1 = Whg + (size_t)(n0 + ra) * K + go1;
  const uint16_t* pWl0 = Wlg + (size_t)(n0 + ra) * K + go0;
  const uint16_t* pWl1 = Wlg + (size_t)(n0 + ra) * K + go1;
  const int ch8 = (b8 ^ (mi & 3)) * 8;
  f32x4 acc[4][4] = {};
  uint4 ah0A, ah1A, al0A, al1A, wh0A, wh1A, wl0A, wl1A;
  uint4 ah0B, ah1B, al0B, al1B, wh0B, wh1B, wl0B, wl1B;

#define GLOAD(S, k0) do {                                                      \
    ah0##S = *(const uint4*)(pAh0 + (k0));                                     \
    ah1##S = *(const uint4*)(pAh1 + (k0));                                     \
    al0##S = *(const uint4*)(pAl0 + (k0));                                     \
    al1##S = *(const uint4*)(pAl1 + (k0));                                     \
    wh0##S = *(const uint4*)(pWh0 + (k0));                                     \
    wh1##S = *(const uint4*)(pWh1 + (k0));                                     \
    wl0##S = *(const uint4*)(pWl0 + (k0));                                     \
    wl1##S = *(const uint4*)(pWl1 + (k0));                                     \
  } while (0)
#define GWRITE(S) do {                                                         \
    *(uint4*)&Ah[ra][sa0] = ah0##S; *(uint4*)&Ah[ra][sa1] = ah1##S;            \
    *(uint4*)&Al[ra][sa0] = al0##S; *(uint4*)&Al[ra][sa1] = al1##S;            \
    *(uint4*)&Wh[ra][sa0] = wh0##S; *(uint4*)&Wh[ra][sa1] = wh1##S;            \
    *(uint4*)&Wl[ra][sa0] = wl0##S; *(uint4*)&Wl[ra][sa1] = wl1##S;            \
  } while (0)
#define GCOMPUTE() do {                                                        \
    bf16x8 xah[4], xal[4], xbh[4], xbl[4];                                     \
    _Pragma("unroll")                                                          \
    for (int fm = 0; fm < 4; fm++) {                                           \
      xah[fm] = *(const bf16x8*)&Ah[wr * 64 + fm * 16 + mi][ch8];              \
      xal[fm] = *(const bf16x8*)&Al[wr * 64 + fm * 16 + mi][ch8];              \
    }                                                                          \
    _Pragma("unroll")                                                          \
    for (int fn = 0; fn < 4; fn++) {                                           \
      xbh[fn] = *(const bf16x8*)&Wh[wc * 64 + fn * 16 + mi][ch8];              \
      xbl[fn] = *(const bf16x8*)&Wl[wc * 64 + fn * 16 + mi][ch8];              \
    }                                                                          \
    _Pragma("unroll")                                                          \
    for (int fm = 0; fm < 4; fm++)                                             \
      _Pragma("unroll")                                                        \
      for (int fn = 0; fn < 4; fn++) {                                         \
        acc[fm][fn] = MFMA_BF16(xal[fm], xbh[fn], acc[fm][fn], 0, 0, 0);       \
        acc[fm][fn] = MFMA_BF16(xah[fm], xbl[fn], acc[fm][fn], 0, 0, 0);       \
        acc[fm][fn] = MFMA_BF16(xah[fm], xbh[fn], acc[fm][fn], 0, 0, 0);       \
      }                                                                        \
  } while (0)

  GLOAD(A, 0);
  GWRITE(A);           // LDS <- tile 0
  GLOAD(B, 32);        // B <- tile 1
  for (int k0 = 0; k0 < K; k0 += 64) {
    __syncthreads();   // tile k0 visible
    GCOMPUTE();
    __syncthreads();
    GWRITE(B);                              // LDS <- k0+32 (always valid)
    if (k0 + 64 < K) GLOAD(A, k0 + 64);     // A <- k0+64
    __syncthreads();   // tile k0+32 visible
    GCOMPUTE();
    __syncthreads();
    if (k0 + 64 < K) GWRITE(A);             // LDS <- k0+64
    if (k0 + 96 < K) GLOAD(B, k0 + 96);     // B <- k0+96
  }
#undef GLOAD
#undef GWRITE
#undef GCOMPUTE
#pragma unroll
  for (int fm = 0; fm < 4; fm++)
#pragma unroll
    for (int fn = 0; fn < 4; fn++)
#pragma unroll
      for (int rr = 0; rr < 4; rr++) {
        int row = m0 + wr * 64 + fm * 16 + b8 * 4 + rr;
        int col = n0 + wc * 64 + fn * 16 + mi;
        float v = acc[fm][fn][rr];
        size_t o = (size_t)row * N + col;
        if (Cph) {
          if (col < scale_cols) v *= 0.125f;
          uint16_t hv = f2bf(v);
          Cph[o] = hv;
          Cpl[o] = f2bf(v - __uint_as_float((uint32_t)hv << 16));
        } else {
          if (res) v += res[o];
          C[o] = v;
        }
      }
}

// ---------------- flash attention: QBLK=128, NO-MAX softmax, l via ones-MFMA, plane inputs ----------------
template <bool CAUSAL>
__global__ __launch_bounds__(256, 3) void k_fattn(
    const uint16_t* __restrict__ qhg, const uint16_t* __restrict__ qlg, int qs,
    const uint16_t* __restrict__ khg, const uint16_t* __restrict__ klg, int ks_, int khdiv,
    const uint16_t* __restrict__ vhg, const uint16_t* __restrict__ vlg, int nvrows,
    uint16_t* __restrict__ yhg, uint16_t* __restrict__ ylg) {
  __shared__ uint16_t Ksh[64][68], Ksl[64][68];
  __shared__ uint16_t Vsh[64][68], Vsl[64][68];
  __shared__ uint32_t Ps[4][32][36];
  const int h = blockIdx.y, b = blockIdx.z;
  const int qt = CAUSAL ? ((blockIdx.x + h + 2 * b) & 7) : blockIdx.x;
  const int tid = threadIdx.x, wv = tid >> 6, ln = tid & 63, mi = ln & 15, b8 = ln >> 4;
  const int koff = (h / khdiv) * 64;
  const uint16_t* kbh = khg + (size_t)b * T_ * ks_ + koff;
  const uint16_t* kbl = klg + (size_t)b * T_ * ks_ + koff;
  const uint16_t* vbh = vhg + ((size_t)b * nvrows + koff) * T_;
  const uint16_t* vbl = vlg + ((size_t)b * nvrows + koff) * T_;

  bf16x8 qh[2][2], ql[2][2];   // [u][k2]
#pragma unroll
  for (int u = 0; u < 2; u++)
#pragma unroll
    for (int k2 = 0; k2 < 2; k2++) {
      size_t o = (size_t)(b * T_ + qt * 128 + wv * 32 + u * 16 + mi) * qs + h * 64 + k2 * 32 + b8 * 8;
      qh[u][k2] = *(const bf16x8*)&qhg[o];
      ql[u][k2] = *(const bf16x8*)&qlg[o];
    }

  PK8 ONE_;
  ONE_.u[0] = 0x3F803F80u; ONE_.u[1] = 0x3F803F80u;
  ONE_.u[2] = 0x3F803F80u; ONE_.u[3] = 0x3F803F80u;
  const bf16x8 ones = ONE_.v;

  f32x4 lacc[2] = {};
  f32x4 o[2][4] = {};

  const int nkt = CAUSAL ? (2 * qt + 2) : (T_ / 64);
  for (int kt = 0; kt < nkt; kt++) {
    __syncthreads();
    {
      int rr = tid >> 2, cc = (tid & 3) * 16;
      size_t ko = (size_t)(kt * 64 + rr) * ks_ + cc;
      *(uint4*)&Ksh[rr][cc]     = *(const uint4*)&kbh[ko];
      *(uint4*)&Ksh[rr][cc + 8] = *(const uint4*)&kbh[ko + 8];
      *(uint4*)&Ksl[rr][cc]     = *(const uint4*)&kbl[ko];
      *(uint4*)&Ksl[rr][cc + 8] = *(const uint4*)&kbl[ko + 8];
      size_t vo = (size_t)rr * T_ + kt * 64 + cc;
      *(uint4*)&Vsh[rr][cc]     = *(const uint4*)&vbh[vo];
      *(uint4*)&Vsh[rr][cc + 8] = *(const uint4*)&vbh[vo + 8];
      *(uint4*)&Vsl[rr][cc]     = *(const uint4*)&vbl[vo];
      *(uint4*)&Vsl[rr][cc + 8] = *(const uint4*)&vbl[vo + 8];
    }
    __syncthreads();
#pragma unroll
    for (int s = 0; s < 2; s++) {
      bf16x8 kh[2][2], kl[2][2];  // [nf][k2]
#pragma unroll
      for (int nf = 0; nf < 2; nf++)
#pragma unroll
        for (int k2 = 0; k2 < 2; k2++) {
          int rrow = s * 32 + nf * 16 + mi, ccol = k2 * 32 + b8 * 8;
          kh[nf][k2] = *(const bf16x8*)&Ksh[rrow][ccol];
          kl[nf][k2] = *(const bf16x8*)&Ksl[rrow][ccol];
        }
      f32x4 a[2][2] = {};  // [u][nf]
#pragma unroll
      for (int u = 0; u < 2; u++)
#pragma unroll
        for (int nf = 0; nf < 2; nf++)
#pragma unroll
          for (int k2 = 0; k2 < 2; k2++) {
            a[u][nf] = MFMA_BF16(ql[u][k2], kh[nf][k2], a[u][nf], 0, 0, 0);
            a[u][nf] = MFMA_BF16(qh[u][k2], kl[nf][k2], a[u][nf], 0, 0, 0);
            a[u][nf] = MFMA_BF16(qh[u][k2], kh[nf][k2], a[u][nf], 0, 0, 0);
          }
      if (CAUSAL && kt >= 2 * qt) {
        int kg = kt * 64 + s * 32 + mi;
#pragma unroll
        for (int u = 0; u < 2; u++) {
          int qg = qt * 128 + wv * 32 + u * 16 + b8 * 4;
#pragma unroll
          for (int r = 0; r < 4; r++) {
            if (kg > qg + r)      a[u][0][r] = -1e30f;
            if (kg + 16 > qg + r) a[u][1][r] = -1e30f;
          }
        }
      }
#pragma unroll
      for (int u = 0; u < 2; u++) {
#pragma unroll
        for (int r = 0; r < 4; r++) {
          a[u][0][r] = __expf(a[u][0][r]);
          a[u][1][r] = __expf(a[u][1][r]);
        }
#pragma unroll
        for (int r = 0; r < 4; r++) {
          uint32_t Hw, Lw;
          asm("v_cvt_pk_bf16_f32 %0, %1, %2" : "=v"(Hw) : "v"(a[u][0][r]), "v"(a[u][1][r]));
          float h0 = __uint_as_float(Hw << 16);
          float h1 = __uint_as_float(Hw & 0xffff0000u);
          float r0 = a[u][0][r] - h0, r1 = a[u][1][r] - h1;
          asm("v_cvt_pk_bf16_f32 %0, %1, %2" : "=v"(Lw) : "v"(r0), "v"(r1));
          Ps[wv][u * 16 + b8 * 4 + r][mi]      = __builtin_amdgcn_perm(Hw, Lw, 0x05040100u);
          Ps[wv][u * 16 + b8 * 4 + r][16 + mi] = __builtin_amdgcn_perm(Hw, Lw, 0x07060302u);
        }
      }
      // PV (+ l row-sum via ones-MFMA on the matrix pipe)
      bf16x8 ph[2], pl[2];
#pragma unroll
      for (int u = 0; u < 2; u++) {
        const uint32_t* p = &Ps[wv][u * 16 + mi][b8 * 8];
        unpack8(*(const uint4*)p, *(const uint4*)(p + 4), ph[u], pl[u]);
      }
#pragma unroll
      for (int u = 0; u < 2; u++) {
        lacc[u] = MFMA_BF16(pl[u], ones, lacc[u], 0, 0, 0);
        lacc[u] = MFMA_BF16(ph[u], ones, lacc[u], 0, 0, 0);
      }
#pragma unroll
      for (int f = 0; f < 4; f++) {
        int rrow = f * 16 + mi, ccol = s * 32 + b8 * 8;
        bf16x8 vh = *(const bf16x8*)&Vsh[rrow][ccol];
        bf16x8 vl = *(const bf16x8*)&Vsl[rrow][ccol];
#pragma unroll
        for (int u = 0; u < 2; u++) {
          o[u][f] = MFMA_BF16(pl[u], vh, o[u][f], 0, 0, 0);
          o[u][f] = MFMA_BF16(ph[u], vl, o[u][f], 0, 0, 0);
          o[u][f] = MFMA_BF16(ph[u], vh, o[u][f], 0, 0, 0);
        }
      }
    }
  }
#pragma unroll
  for (int u = 0; u < 2; u++)
#pragma unroll
    for (int r = 0; r < 4; r++) {
      float inv = 1.0f / lacc[u][r];
      int row = qt * 128 + wv * 32 + u * 16 + b8 * 4 + r;
#pragma unroll
      for (int f = 0; f < 4; f++) {
        size_t idx = (size_t)(b * T_ + row) * D_ + h * 64 + f * 16 + mi;
        float v = o[u][f][r] * inv;
        uint16_t hv = f2bf(v);
        yhg[idx] = hv;
        ylg[idx] = f2bf(v - __uint_as_float((uint32_t)hv << 16));
      }
    }
}

__global__ __launch_bounds__(256) void k_bucket(const int* __restrict__ idx, int* __restrict__ cnt,
                                                int* __restrict__ lists) {
  int tok = blockIdx.x * 256 + threadIdx.x;
  int e = idx[tok];
  int p = atomicAdd(&cnt[e], 1);
  lists[e * NT + p] = tok;
}

// ---------------- MoE GEMM1: 64 x 128, BK=64, distance-2 reg-prefetch, expert->XCD confinement ----------------
// 1D grid, bid = inner*8 + e: round-robin dispatch puts all blocks of expert e on XCD e,
// so each XCD's L2 holds ONE expert's w1t slice + token rows (fill-traffic dedup).
__global__ __launch_bounds__(256) void k_moe1(const uint16_t* __restrict__ xmbf, const uint16_t* __restrict__ w1t,
                                              const float* __restrict__ b1, const int* __restrict__ cnt,
                                              const int* __restrict__ lists, uint16_t* __restrict__ hbf) {
  int bid = blockIdx.x;
  int e = bid & 7;
  int inner = bid >> 3;
  int n0 = (inner & 31) * 128;     // F/128 = 32 n-tiles
  int m0 = (inner >> 5) * 64;      // NT/64 = 64 m-rows
  int c = cnt[e];
  if (m0 >= c) return;
  __shared__ uint16_t As[64][72];
  __shared__ uint16_t Ws[128][72];
  __shared__ int toks[64];
  int tid = threadIdx.x, wv = tid >> 6, ln = tid & 63, mi = ln & 15, b8 = ln >> 4;
  if (tid < 64) toks[tid] = (m0 + tid < c) ? lists[e * NT + m0 + tid] : -1;
  __syncthreads();
  int ra = tid >> 2, ca = (tid & 3) * 16;
  int rw = tid >> 1, cw = (tid & 1) * 32;
  int tk = toks[ra];
  const uint16_t* asrc = (tk >= 0) ? (xmbf + (size_t)tk * D_ + ca) : nullptr;
  const uint16_t* wsrc = w1t + (size_t)e * F_ * D_ + (size_t)(n0 + rw) * D_ + cw;
  f32x4 acc[4][2] = {};
  uint4 a0A = make_uint4(0,0,0,0), a1A = make_uint4(0,0,0,0), w0A, w1A, w2A, w3A;
  uint4 a0B = make_uint4(0,0,0,0), a1B = make_uint4(0,0,0,0), w0B, w1B, w2B, w3B;

#define M1LOAD(S, k0) do {                                                     \
    if (asrc) { a0##S = *(const uint4*)(asrc + (k0)); a1##S = *(const uint4*)(asrc + (k0) + 8); } \
    w0##S = *(const uint4*)(wsrc + (k0));      w1##S = *(const uint4*)(wsrc + (k0) + 8);  \
    w2##S = *(const uint4*)(wsrc + (k0) + 16); w3##S = *(const uint4*)(wsrc + (k0) + 24); \
  } while (0)
#define M1WRITE(S) do {                                                        \
    *(uint4*)&As[ra][ca] = a0##S;       *(uint4*)&As[ra][ca + 8] = a1##S;      \
    *(uint4*)&Ws[rw][cw] = w0##S;       *(uint4*)&Ws[rw][cw + 8] = w1##S;      \
    *(uint4*)&Ws[rw][cw + 16] = w2##S;  *(uint4*)&Ws[rw][cw + 24] = w3##S;     \
  } while (0)
#define M1COMPUTE() do {                                                       \
    _Pragma("unroll")                                                          \
    for (int ks = 0; ks < 2; ks++) {                                           \
      bf16x8 a[4], bb[2];                                                      \
      _Pragma("unroll")                                                        \
      for (int fm = 0; fm < 4; fm++)                                           \
        a[fm] = *(const bf16x8*)&As[fm * 16 + mi][ks * 32 + b8 * 8];           \
      _Pragma("unroll")                                                        \
      for (int nf = 0; nf < 2; nf++)                                           \
        bb[nf] = *(const bf16x8*)&Ws[wv * 32 + nf * 16 + mi][ks * 32 + b8 * 8];\
      _Pragma("unroll")                                                        \
      for (int fm = 0; fm < 4; fm++)                                           \
        _Pragma("unroll")                                                      \
        for (int nf = 0; nf < 2; nf++)                                         \
          acc[fm][nf] = MFMA_BF16(a[fm], bb[nf], acc[fm][nf], 0, 0, 0);        \
    }                                                                          \
  } while (0)

  M1LOAD(A, 0);
  M1WRITE(A);
  M1LOAD(B, 64);
  for (int k0 = 0; k0 < D_; k0 += 128) {
    __syncthreads();
    M1COMPUTE();
    __syncthreads();
    M1WRITE(B);
    if (k0 + 128 < D_) M1LOAD(A, k0 + 128);
    __syncthreads();
    M1COMPUTE();
    __syncthreads();
    if (k0 + 128 < D_) M1WRITE(A);
    if (k0 + 192 < D_) M1LOAD(B, k0 + 192);
  }
#undef M1LOAD
#undef M1WRITE
#undef M1COMPUTE
#pragma unroll
  for (int fm = 0; fm < 4; fm++)
#pragma unroll
    for (int nf = 0; nf < 2; nf++)
#pragma unroll
      for (int rr = 0; rr < 4; rr++) {
        int rt = fm * 16 + b8 * 4 + rr;
        if (m0 + rt < c) {
          int tok = toks[rt];
          int col = n0 + wv * 32 + nf * 16 + mi;
          float v = acc[fm][nf][rr] + b1[e * F_ + col];
          v = v / (1.0f + expf(-v));
          hbf[(size_t)tok * F_ + col] = f2bf(v);
        }
      }
}

// ---------------- MoE GEMM2: 64 x 64, BK=64, distance-2 reg-prefetch, expert->XCD confinement ----------------
__global__ __launch_bounds__(256) void k_moe2(const uint16_t* __restrict__ hbf, const uint16_t* __restrict__ w2t,
                                              const float* __restrict__ b2, const float* __restrict__ x2,
                                              const float* __restrict__ sc, const int* __restrict__ cnt,
                                              const int* __restrict__ lists, float* __restrict__ out) {
  int bid = blockIdx.x;
  int e = bid & 7;
  int inner = bid >> 3;
  int n0 = (inner & 15) * 64;      // D/64 = 16 n-tiles
  int m0 = (inner >> 4) * 64;      // NT/64 = 64 m-rows
  int c = cnt[e];
  if (m0 >= c) return;
  __shared__ uint16_t As[64][72];
  __shared__ uint16_t Ws[64][72];
  __shared__ int toks[64];
  int tid = threadIdx.x, wv = tid >> 6, ln = tid & 63, mi = ln & 15, b8 = ln >> 4;
  if (tid < 64) toks[tid] = (m0 + tid < c) ? lists[e * NT + m0 + tid] : -1;
  __syncthreads();
  int r = tid >> 2, c16 = (tid & 3) * 16;
  int tk = toks[r];
  const uint16_t* asrc = (tk >= 0) ? (hbf + (size_t)tk * F_ + c16) : nullptr;
  const uint16_t* wsrc = w2t + (size_t)e * D_ * F_ + (size_t)(n0 + r) * F_ + c16;
  f32x4 acc[4] = {};
  uint4 a0A = make_uint4(0,0,0,0), a1A = make_uint4(0,0,0,0), w0A, w1A;
  uint4 a0B = make_uint4(0,0,0,0), a1B = make_uint4(0,0,0,0), w0B, w1B;

#define M2LOAD(S, k0) do {                                                     \
    if (asrc) { a0##S = *(const uint4*)(asrc + (k0)); a1##S = *(const uint4*)(asrc + (k0) + 8); } \
    w0##S = *(const uint4*)(wsrc + (k0)); w1##S = *(const uint4*)(wsrc + (k0) + 8); \
  } while (0)
#define M2WRITE(S) do {                                                        \
    *(uint4*)&As[r][c16] = a0##S; *(uint4*)&As[r][c16 + 8] = a1##S;            \
    *(uint4*)&Ws[r][c16] = w0##S; *(uint4*)&Ws[r][c16 + 8] = w1##S;            \
  } while (0)
#define M2COMPUTE() do {                                                       \
    _Pragma("unroll")                                                          \
    for (int ks = 0; ks < 2; ks++) {                                           \
      bf16x8 a = *(const bf16x8*)&As[wv * 16 + mi][ks * 32 + b8 * 8];          \
      _Pragma("unroll")                                                        \
      for (int fn = 0; fn < 4; fn++) {                                         \
        bf16x8 bb = *(const bf16x8*)&Ws[fn * 16 + mi][ks * 32 + b8 * 8];       \
        acc[fn] = MFMA_BF16(a, bb, acc[fn], 0, 0, 0);                          \
      }                                                                        \
    }                                                                          \
  } while (0)

  M2LOAD(A, 0);
  M2WRITE(A);
  M2LOAD(B, 64);
  for (int k0 = 0; k0 < F_; k0 += 128) {
    __syncthreads();
    M2COMPUTE();
    __syncthreads();
    M2WRITE(B);
    if (k0 + 128 < F_) M2LOAD(A, k0 + 128);
    __syncthreads();
    M2COMPUTE();
    __syncthreads();
    if (k0 + 128 < F_) M2WRITE(A);
    if (k0 + 192 < F_) M2LOAD(B, k0 + 192);
  }
#undef M2LOAD
#undef M2WRITE
#undef M2COMPUTE
#pragma unroll
  for (int fn = 0; fn < 4; fn++)
#pragma unroll
    for (int rr = 0; rr < 4; rr++) {
      int rt = wv * 16 + b8 * 4 + rr;
      if (m0 + rt < c) {
        int tok = toks[rt];
        int col = n0 + fn * 16 + mi;
        float v = acc[fn][rr] + b2[e * D_ + col];
        out[(size_t)tok * D_ + col] = x2[(size_t)tok * D_ + col] + sc[tok] * v;
      }
    }
}

extern "C" void kernel_launch(void* const* d_in, const int* in_sizes, int n_in,
                              void* d_out, int out_size, void* d_ws, size_t ws_size,
                              hipStream_t stream) {
  const float* x       = (const float*)d_in[0];
  const float* k_ctx   = (const float*)d_in[1];
  const float* v_ctx   = (const float*)d_in[2];
  const float* sa_nw   = (const float*)d_in[3];
  const float* w_qkv   = (const float*)d_in[4];
  const float* sa_wout = (const float*)d_in[5];
  const float* ca_nw   = (const float*)d_in[6];
  const float* w_q     = (const float*)d_in[7];
  const float* ca_wout = (const float*)d_in[8];
  const float* moe_nw  = (const float*)d_in[9];
  const float* w_gate  = (const float*)d_in[10];
  const float* w1      = (const float*)d_in[11];
  const float* b1      = (const float*)d_in[12];
  const float* w2      = (const float*)d_in[13];
  const float* b2      = (const float*)d_in[14];
  float* out = (float*)d_out;
  (void)in_sizes; (void)n_in; (void)out_size; (void)ws_size;

  char* ws = (char*)d_ws;
  size_t off = 0;
  auto alloc = [&](size_t bytes) { char* p = ws + off; off += (bytes + 255) & ~(size_t)255; return p; };
  uint16_t* xnh   = (uint16_t*)alloc((size_t)NT * D_ * 2);
  uint16_t* xnl   = (uint16_t*)alloc((size_t)NT * D_ * 2);
  uint16_t* yh    = (uint16_t*)alloc((size_t)NT * D_ * 2);
  uint16_t* yl    = (uint16_t*)alloc((size_t)NT * D_ * 2);
  float*    x1    = (float*)alloc((size_t)NT * D_ * 4);
  uint16_t* qkvh  = (uint16_t*)alloc((size_t)NT * 3 * D_ * 2);   // 24 MB
  uint16_t* qkvl  = (uint16_t*)alloc((size_t)NT * 3 * D_ * 2);   // 24 MB
  float* x2 = (float*)qkvh;
  uint16_t* qch = qkvl;
  uint16_t* qcl = qkvl + (size_t)NT * D_;
  uint16_t* wqkvTh = (uint16_t*)alloc((size_t)D_ * 3 * D_ * 2);
  uint16_t* wqkvTl = (uint16_t*)alloc((size_t)D_ * 3 * D_ * 2);
  uint16_t* sawTh  = (uint16_t*)alloc((size_t)D_ * D_ * 2);
  uint16_t* sawTl  = (uint16_t*)alloc((size_t)D_ * D_ * 2);
  uint16_t* wqTh   = (uint16_t*)alloc((size_t)D_ * D_ * 2);
  uint16_t* wqTl   = (uint16_t*)alloc((size_t)D_ * D_ * 2);
  uint16_t* cawTh  = (uint16_t*)alloc((size_t)D_ * D_ * 2);
  uint16_t* cawTl  = (uint16_t*)alloc((size_t)D_ * D_ * 2);
  uint16_t* w1t   = (uint16_t*)alloc((size_t)E_ * D_ * F_ * 2);
  uint16_t* w2t   = (uint16_t*)alloc((size_t)E_ * D_ * F_ * 2);
  uint16_t* hbf   = (uint16_t*)alloc((size_t)NT * F_ * 2);   // 32 MB, MoE-phase only
  uint16_t* vth   = (uint16_t*)hbf;                                        // 8 MB
  uint16_t* vtl   = vth + (size_t)NT * D_;                                 // 8 MB
  uint16_t* kch   = (uint16_t*)((char*)hbf + (size_t)16 * 1024 * 1024);    // 2 MB
  uint16_t* kcl   = (uint16_t*)((char*)hbf + (size_t)18 * 1024 * 1024);    // 2 MB
  uint16_t* vcth  = (uint16_t*)((char*)hbf + (size_t)20 * 1024 * 1024);    // 2 MB
  uint16_t* vctl  = (uint16_t*)((char*)hbf + (size_t)22 * 1024 * 1024);    // 2 MB
  uint16_t* xmbf  = (uint16_t*)alloc((size_t)NT * D_ * 2);
  int*   idx   = (int*)alloc(NT * 4);
  float* scb   = (float*)alloc(NT * 4);
  int*   cnt   = (int*)alloc(256);
  int*   lists = (int*)alloc((size_t)E_ * NT * 4);

  // weight prep (merged launches)
  k_pack_all<<<dim3(32, 32, 6), 256, 0, stream>>>(w_qkv, sa_wout, w_q, ca_wout,
                                                  wqkvTh, wqkvTl, sawTh, sawTl,
                                                  wqTh, wqTl, cawTh, cawTl);
  k_bf_t2<<<dim3(1024, 1, 16), 256, 0, stream>>>(w1, w2, w1t, w2t);
  // cross-attn K/V prep (planes)
  k_packf2<<<(B_ * T_ * 256) / 1024, 256, 0, stream>>>(k_ctx, kch, kcl);
  k_tf32<<<dim3(T_ / 32, 256 / 32, B_), 256, 0, stream>>>(v_ctx, vcth, vctl);

  // self-attention block
  k_rms<<<NT, 256, 0, stream>>>(x, sa_nw, xnh, xnl, nullptr, nullptr, nullptr);
  k_gemm_split<<<dim3(3 * D_ / GBN, NT / GBM), 256, 0, stream>>>(xnh, xnl, wqkvTh, wqkvTl, nullptr, nullptr, qkvh, qkvl, 1024, NT, 3 * D_, D_);
  k_t16<<<dim3(T_ / 64, D_ / 64, B_), 256, 0, stream>>>(qkvh, qkvl, vth, vtl);
  k_fattn<true><<<dim3(T_ / 128, H_, B_), 256, 0, stream>>>(qkvh, qkvl, 3072, qkvh + 1024, qkvl + 1024, 3072, 1, vth, vtl, 1024, yh, yl);
  k_gemm_split<<<dim3(D_ / GBN, NT / GBM), 256, 0, stream>>>(yh, yl, sawTh, sawTl, x1, x, nullptr, nullptr, 0, NT, D_, D_);

  // cross-attention block (GQA)
  k_rms<<<NT, 256, 0, stream>>>(x1, ca_nw, xnh, xnl, nullptr, nullptr, nullptr);
  k_gemm_split<<<dim3(D_ / GBN, NT / GBM), 256, 0, stream>>>(xnh, xnl, wqTh, wqTl, nullptr, nullptr, qch, qcl, 1024, NT, D_, D_);
  k_fattn<false><<<dim3(T_ / 128, H_, B_), 256, 0, stream>>>(qch, qcl, 1024, kch, kcl, 256, 4, vcth, vctl, 256, yh, yl);
  k_gemm_split<<<dim3(D_ / GBN, NT / GBM), 256, 0, stream>>>(yh, yl, cawTh, cawTl, x2, x1, nullptr, nullptr, 0, NT, D_, D_);

  // MoE (gate fused into RMSNorm); expert->XCD confined 1D grids
  k_rms<<<NT, 256, 0, stream>>>(x2, moe_nw, xmbf, nullptr, w_gate, idx, scb);
  hipMemsetAsync(cnt, 0, 32, stream);
  k_bucket<<<NT / 256, 256, 0, stream>>>(idx, cnt, lists);
  k_moe1<<<dim3(8 * (F_ / 128) * (NT / 64)), 256, 0, stream>>>(xmbf, w1t, b1, cnt, lists, hbf);
  k_moe2<<<dim3(8 * (D_ / 64) * (NT / 64)), 256, 0, stream>>>(hbf, w2t, b2, x2, scb, cnt, lists, out);
}

// Round 26
// 693.950 us; speedup vs baseline: 1.0255x; 1.0255x over previous
//
#include <hip/hip_runtime.h>
#include <hip/hip_bf16.h>
#include <stdint.h>

#define B_  4
#define T_  1024
#define D_  1024
#define H_  16
#define DH  64
#define F_  4096
#define E_  8
#define NT  (B_*T_)          // 4096 tokens

typedef float f32x4 __attribute__((ext_vector_type(4)));
typedef short bf16x8 __attribute__((ext_vector_type(8)));
#define MFMA_BF16 __builtin_amdgcn_mfma_f32_16x16x32_bf16

union PK8 { uint32_t u[4]; bf16x8 v; };

// ---- bf16 helpers: RNE round, split f32 -> hi/lo bf16 ----
static __device__ __forceinline__ uint16_t f2bf(float f) {
  uint32_t u = __float_as_uint(f);
  u += 0x7FFFu + ((u >> 16) & 1u);
  return (uint16_t)(u >> 16);
}
// unpack 8 packed u32 -> hi / lo bf16x8 (used only for P tiles in fattn)
static __device__ __forceinline__ void unpack8(const uint4 p0, const uint4 p1, bf16x8 &hi, bf16x8 &lo) {
  PK8 H, L;
  H.u[0] = __builtin_amdgcn_perm(p0.y, p0.x, 0x07060302u);
  L.u[0] = __builtin_amdgcn_perm(p0.y, p0.x, 0x05040100u);
  H.u[1] = __builtin_amdgcn_perm(p0.w, p0.z, 0x07060302u);
  L.u[1] = __builtin_amdgcn_perm(p0.w, p0.z, 0x05040100u);
  H.u[2] = __builtin_amdgcn_perm(p1.y, p1.x, 0x07060302u);
  L.u[2] = __builtin_amdgcn_perm(p1.y, p1.x, 0x05040100u);
  H.u[3] = __builtin_amdgcn_perm(p1.w, p1.z, 0x07060302u);
  L.u[3] = __builtin_amdgcn_perm(p1.w, p1.z, 0x05040100u);
  hi = H.v; lo = L.v;
}

// ---------------- merged dense-weight prep: transpose [K=1024][N] -> [N][1024] hi/lo planes ----------------
__global__ __launch_bounds__(256) void k_pack_all(
    const float* __restrict__ wqkv, const float* __restrict__ saw,
    const float* __restrict__ wq,   const float* __restrict__ caw,
    uint16_t* __restrict__ qkvTh, uint16_t* __restrict__ qkvTl,
    uint16_t* __restrict__ sawTh, uint16_t* __restrict__ sawTl,
    uint16_t* __restrict__ wqTh,  uint16_t* __restrict__ wqTl,
    uint16_t* __restrict__ cawTh, uint16_t* __restrict__ cawTl) {
  __shared__ float t[32][33];
  int z = blockIdx.z;
  const float* in; uint16_t *oh, *ol; int N, nbase;
  if (z < 3)       { in = wqkv; oh = qkvTh; ol = qkvTl; N = 3072; nbase = z * 1024; }
  else if (z == 3) { in = saw;  oh = sawTh; ol = sawTl; N = 1024; nbase = 0; }
  else if (z == 4) { in = wq;   oh = wqTh;  ol = wqTl;  N = 1024; nbase = 0; }
  else             { in = caw;  oh = cawTh; ol = cawTl; N = 1024; nbase = 0; }
  int n0 = nbase + blockIdx.x * 32, k0 = blockIdx.y * 32;
  int tx = threadIdx.x & 31, ty = threadIdx.x >> 5;
#pragma unroll
  for (int i = 0; i < 32; i += 8) t[ty + i][tx] = in[(size_t)(k0 + ty + i) * N + n0 + tx];
  __syncthreads();
#pragma unroll
  for (int i = 0; i < 32; i += 8) {
    float v = t[tx][ty + i];
    uint16_t h = f2bf(v);
    uint16_t l = f2bf(v - __uint_as_float((uint32_t)h << 16));
    size_t o = (size_t)(n0 + ty + i) * 1024 + k0 + tx;
    oh[o] = h; ol[o] = l;
  }
}

// merged MoE weight prep: w1 [D][F] and w2 [F][D] -> transposed bf16; z = which*8 + e
__global__ __launch_bounds__(256) void k_bf_t2(const float* __restrict__ w1, const float* __restrict__ w2,
                                               uint16_t* __restrict__ w1t, uint16_t* __restrict__ w2t) {
  __shared__ float t[64][65];
  int z = blockIdx.z;
  int which = z >> 3, e = z & 7;
  const float* in = which ? w2 : w1;
  uint16_t* out = which ? w2t : w1t;
  int K = which ? F_ : D_, N = which ? D_ : F_;
  const size_t mo = (size_t)e * (size_t)D_ * F_;
  in += mo; out += mo;
  int tile = blockIdx.x;
  int n0, k0;
  if (which) { n0 = (tile & 15) * 64; k0 = (tile >> 4) * 64; }
  else       { n0 = (tile & 63) * 64; k0 = (tile >> 6) * 64; }
  int tr = threadIdx.x >> 4;
  int tc = (threadIdx.x & 15) * 4;
#pragma unroll
  for (int i = 0; i < 64; i += 16) {
    float4 v = *(const float4*)&in[(size_t)(k0 + tr + i) * N + n0 + tc];
    t[tr + i][tc] = v.x; t[tr + i][tc + 1] = v.y; t[tr + i][tc + 2] = v.z; t[tr + i][tc + 3] = v.w;
  }
  __syncthreads();
#pragma unroll
  for (int i = 0; i < 64; i += 16) {
    int n = tr + i;
    uint16_t b0 = f2bf(t[tc][n]), b1 = f2bf(t[tc + 1][n]);
    uint16_t b2 = f2bf(t[tc + 2][n]), b3 = f2bf(t[tc + 3][n]);
    uint2 wv;
    wv.x = ((uint32_t)b1 << 16) | b0;
    wv.y = ((uint32_t)b3 << 16) | b2;
    *(uint2*)&out[(size_t)(n0 + n) * K + k0 + tc] = wv;
  }
}

// u16 plane transpose of v-region of qkv planes: [b][t][2048+c] -> vt[(b*1024+c)][t]
__global__ __launch_bounds__(256) void k_t16(const uint16_t* __restrict__ inh, const uint16_t* __restrict__ inl,
                                             uint16_t* __restrict__ outh, uint16_t* __restrict__ outl) {
  __shared__ uint16_t th[64][68], tl[64][68];
  int b = blockIdx.z, t0 = blockIdx.x * 64, c0 = blockIdx.y * 64;
  int tr = threadIdx.x >> 4;
  int tc = (threadIdx.x & 15) * 4;
#pragma unroll
  for (int i = 0; i < 64; i += 16) {
    size_t src = (size_t)(b * T_ + t0 + tr + i) * 3072 + 2048 + c0 + tc;
    *(uint2*)&th[tr + i][tc] = *(const uint2*)&inh[src];
    *(uint2*)&tl[tr + i][tc] = *(const uint2*)&inl[src];
  }
  __syncthreads();
#pragma unroll
  for (int i = 0; i < 64; i += 16) {
    int n = tr + i;
    size_t dst = (size_t)(b * 1024 + c0 + n) * T_ + t0 + tc;
    uint2 ph, pl;
    ph.x = ((uint32_t)th[tc + 1][n] << 16) | th[tc][n];
    ph.y = ((uint32_t)th[tc + 3][n] << 16) | th[tc + 2][n];
    pl.x = ((uint32_t)tl[tc + 1][n] << 16) | tl[tc][n];
    pl.y = ((uint32_t)tl[tc + 3][n] << 16) | tl[tc + 2][n];
    *(uint2*)&outh[dst] = ph;
    *(uint2*)&outl[dst] = pl;
  }
}

// elementwise split f32 -> hi/lo planes
__global__ __launch_bounds__(256) void k_packf2(const float* __restrict__ in,
                                                uint16_t* __restrict__ oh, uint16_t* __restrict__ ol) {
  int i = (blockIdx.x * 256 + threadIdx.x) * 4;
  float4 v = *(const float4*)&in[i];
  uint16_t h0 = f2bf(v.x), h1 = f2bf(v.y), h2 = f2bf(v.z), h3 = f2bf(v.w);
  uint2 ph, pl;
  ph.x = ((uint32_t)h1 << 16) | h0;
  ph.y = ((uint32_t)h3 << 16) | h2;
  pl.x = ((uint32_t)f2bf(v.y - __uint_as_float((uint32_t)h1 << 16)) << 16) |
         f2bf(v.x - __uint_as_float((uint32_t)h0 << 16));
  pl.y = ((uint32_t)f2bf(v.w - __uint_as_float((uint32_t)h3 << 16)) << 16) |
         f2bf(v.z - __uint_as_float((uint32_t)h2 << 16));
  *(uint2*)&oh[i] = ph;
  *(uint2*)&ol[i] = pl;
}

// transpose+split: v_ctx f32 [b][t][gc] (gc<256) -> planes [(b*256+gc)][t]
__global__ __launch_bounds__(256) void k_tf32(const float* __restrict__ in,
                                              uint16_t* __restrict__ oh, uint16_t* __restrict__ ol) {
  __shared__ float t[32][33];
  int b = blockIdx.z, t0 = blockIdx.x * 32, c0 = blockIdx.y * 32;
  int tx = threadIdx.x & 31, ty = threadIdx.x >> 5;
#pragma unroll
  for (int i = 0; i < 32; i += 8)
    t[ty + i][tx] = in[(size_t)(b * T_ + t0 + ty + i) * 256 + c0 + tx];
  __syncthreads();
#pragma unroll
  for (int i = 0; i < 32; i += 8) {
    float v = t[tx][ty + i];
    uint16_t h = f2bf(v);
    size_t o = (size_t)(b * 256 + c0 + ty + i) * T_ + t0 + tx;
    oh[o] = h;
    ol[o] = f2bf(v - __uint_as_float((uint32_t)h << 16));
  }
}

// ---------------- RMSNorm (fp32 exact): hi/lo planes; optional fused MoE gate ----------------
__global__ __launch_bounds__(256) void k_rms(const float* __restrict__ x, const float* __restrict__ w,
                                             uint16_t* __restrict__ oh, uint16_t* __restrict__ ol,
                                             const float* __restrict__ wg, int* __restrict__ idxp,
                                             float* __restrict__ scb) {
  int row = blockIdx.x;
  const float* xr = x + (size_t)row * D_;
  int t = threadIdx.x;
  float4 xv = *(const float4*)&xr[t * 4];
  float s = xv.x * xv.x + xv.y * xv.y + xv.z * xv.z + xv.w * xv.w;
#pragma unroll
  for (int o = 32; o; o >>= 1) s += __shfl_xor(s, o, 64);
  __shared__ float ps[4];
  __shared__ float ga[4][8];
  if ((t & 63) == 0) ps[t >> 6] = s;
  __syncthreads();
  s = ps[0] + ps[1] + ps[2] + ps[3];
  float sc = 1.0f / sqrtf(s * (1.0f / (float)D_) + 1e-6f);
  float4 wv = *(const float4*)&w[t * 4];
  float o0 = xv.x * sc * wv.x, o1 = xv.y * sc * wv.y, o2 = xv.z * sc * wv.z, o3 = xv.w * sc * wv.w;
  uint16_t h0 = f2bf(o0), h1 = f2bf(o1), h2 = f2bf(o2), h3 = f2bf(o3);
  if (oh) {
    uint2 ph;
    ph.x = ((uint32_t)h1 << 16) | h0;
    ph.y = ((uint32_t)h3 << 16) | h2;
    *(uint2*)&oh[(size_t)row * D_ + t * 4] = ph;
  }
  if (ol) {
    uint16_t l0 = f2bf(o0 - __uint_as_float((uint32_t)h0 << 16));
    uint16_t l1 = f2bf(o1 - __uint_as_float((uint32_t)h1 << 16));
    uint16_t l2 = f2bf(o2 - __uint_as_float((uint32_t)h2 << 16));
    uint16_t l3 = f2bf(o3 - __uint_as_float((uint32_t)h3 << 16));
    uint2 pl;
    pl.x = ((uint32_t)l1 << 16) | l0;
    pl.y = ((uint32_t)l3 << 16) | l2;
    *(uint2*)&ol[(size_t)row * D_ + t * 4] = pl;
  }
  if (wg) {
    float a[8] = {};
    float ov[4] = {o0, o1, o2, o3};
#pragma unroll
    for (int j = 0; j < 4; j++) {
      const float* wr = &wg[(size_t)(t * 4 + j) * 8];
      float4 wa = *(const float4*)wr, wb = *(const float4*)(wr + 4);
      float v = ov[j];
      a[0] += v * wa.x; a[1] += v * wa.y; a[2] += v * wa.z; a[3] += v * wa.w;
      a[4] += v * wb.x; a[5] += v * wb.y; a[6] += v * wb.z; a[7] += v * wb.w;
    }
#pragma unroll
    for (int e = 0; e < 8; e++)
#pragma unroll
      for (int o = 32; o; o >>= 1) a[e] += __shfl_xor(a[e], o, 64);
    if ((t & 63) == 0)
#pragma unroll
      for (int e = 0; e < 8; e++) ga[t >> 6][e] = a[e];
    __syncthreads();
    if (t == 0) {
      float g[8];
#pragma unroll
      for (int e = 0; e < 8; e++) g[e] = ga[0][e] + ga[1][e] + ga[2][e] + ga[3][e];
      int bi = 0; float bv = g[0];
#pragma unroll
      for (int e = 1; e < 8; e++) if (g[e] > bv) { bv = g[e]; bi = e; }
      float se = 0.f;
#pragma unroll
      for (int e = 0; e < 8; e++) se += expf(g[e] - bv);
      idxp[row] = bi;
      scb[row] = 1.0f / se;
    }
  }
}

// ---------------- split-bf16 GEMM v13: 128x128 register-blocked tile (fm=fn=4), 3-MFMA split ----------------
// 4 waves in 2x2; per wave per 32-K step: 16 ds_read_b128 -> 48 MFMA (ratio 3.0 vs v10's 2.0).
// LDS image: slot cs of row r holds global 16B-chunk cs ^ (r&3); conflict-free fixed-slot writes (v11).
#define GBM 128
#define GBN 128
__global__ __launch_bounds__(256) void k_gemm_split(const uint16_t* __restrict__ Ahg, const uint16_t* __restrict__ Alg,
                                                    const uint16_t* __restrict__ Whg, const uint16_t* __restrict__ Wlg,
                                                    float* __restrict__ C, const float* __restrict__ res,
                                                    uint16_t* __restrict__ Cph, uint16_t* __restrict__ Cpl,
                                                    int scale_cols, int M, int N, int K) {
  __shared__ uint16_t Ah[GBM][32], Al[GBM][32];
  __shared__ uint16_t Wh[GBN][32], Wl[GBN][32];
  int m0 = blockIdx.y * GBM, n0 = blockIdx.x * GBN;
  int tid = threadIdx.x, wv = tid >> 6, ln = tid & 63, mi = ln & 15, b8 = ln >> 4;
  const int wr = wv >> 1, wc = wv & 1;   // 2x2 wave grid, each wave 64x64 output
  // staging: 2 thr/row (128 rows), fixed LDS slots cs0/cs1, swizzled global source (all 4 arrays)
  int ra = tid >> 1, qa = tid & 1;
  const int cs0 = qa * 2 + ((ra >> 1) & 1);
  const int cs1 = cs0 ^ 1;
  const int sa0 = cs0 * 8;
  const int sa1 = cs1 * 8;
  const int go0 = (cs0 ^ (ra & 3)) * 8;
  const int go1 = (cs1 ^ (ra & 3)) * 8;
  const uint16_t* pAh0 = Ahg + (size_t)(m0 + ra) * K + go0;
  const uint16_t* pAh1 = Ahg + (size_t)(m0 + ra) * K + go1;
  const uint16_t* pAl0 = Alg + (size_t)(m0 + ra) * K + go0;
  const uint16_t* pAl1 = Alg + (size_t)(m0 + ra) * K + go1;
  const uint16_t* pWh0 = Whg + (size_t)(n0 + ra) * K + go0;
  const uint16_t* pWh1 = Whg + (size_t)(n0 + ra) * K + go1;
  const uint16_t* pWl0 = Wlg + (size_t)(n0 + ra) * K + go0;
  const uint16_t* pWl1 = Wlg + (size_t)(n0 + ra) * K + go1;
  const int ch8 = (b8 ^ (mi & 3)) * 8;
  f32x4 acc[4][4] = {};
  uint4 ah0A, ah1A, al0A, al1A, wh0A, wh1A, wl0A, wl1A;
  uint4 ah0B, ah1B, al0B, al1B, wh0B, wh1B, wl0B, wl1B;

#define GLOAD(S, k0) do {                                                      \
    ah0##S = *(const uint4*)(pAh0 + (k0));                                     \
    ah1##S = *(const uint4*)(pAh1 + (k0));                                     \
    al0##S = *(const uint4*)(pAl0 + (k0));                                     \
    al1##S = *(const uint4*)(pAl1 + (k0));                                     \
    wh0##S = *(const uint4*)(pWh0 + (k0));                                     \
    wh1##S = *(const uint4*)(pWh1 + (k0));                                     \
    wl0##S = *(const uint4*)(pWl0 + (k0));                                     \
    wl1##S = *(const uint4*)(pWl1 + (k0));                                     \
  } while (0)
#define GWRITE(S) do {                                                         \
    *(uint4*)&Ah[ra][sa0] = ah0##S; *(uint4*)&Ah[ra][sa1] = ah1##S;            \
    *(uint4*)&Al[ra][sa0] = al0##S; *(uint4*)&Al[ra][sa1] = al1##S;            \
    *(uint4*)&Wh[ra][sa0] = wh0##S; *(uint4*)&Wh[ra][sa1] = wh1##S;            \
    *(uint4*)&Wl[ra][sa0] = wl0##S; *(uint4*)&Wl[ra][sa1] = wl1##S;            \
  } while (0)
#define GCOMPUTE() do {                                                        \
    bf16x8 xah[4], xal[4], xbh[4], xbl[4];                                     \
    _Pragma("unroll")                                                          \
    for (int fm = 0; fm < 4; fm++) {                                           \
      xah[fm] = *(const bf16x8*)&Ah[wr * 64 + fm * 16 + mi][ch8];              \
      xal[fm] = *(const bf16x8*)&Al[wr * 64 + fm * 16 + mi][ch8];              \
    }                                                                          \
    _Pragma("unroll")                                                          \
    for (int fn = 0; fn < 4; fn++) {                                           \
      xbh[fn] = *(const bf16x8*)&Wh[wc * 64 + fn * 16 + mi][ch8];              \
      xbl[fn] = *(const bf16x8*)&Wl[wc * 64 + fn * 16 + mi][ch8];              \
    }                                                                          \
    _Pragma("unroll")                                                          \
    for (int fm = 0; fm < 4; fm++)                                             \
      _Pragma("unroll")                                                        \
      for (int fn = 0; fn < 4; fn++) {                                         \
        acc[fm][fn] = MFMA_BF16(xal[fm], xbh[fn], acc[fm][fn], 0, 0, 0);       \
        acc[fm][fn] = MFMA_BF16(xah[fm], xbl[fn], acc[fm][fn], 0, 0, 0);       \
        acc[fm][fn] = MFMA_BF16(xah[fm], xbh[fn], acc[fm][fn], 0, 0, 0);       \
      }                                                                        \
  } while (0)

  GLOAD(A, 0);
  GWRITE(A);           // LDS <- tile 0
  GLOAD(B, 32);        // B <- tile 1
  for (int k0 = 0; k0 < K; k0 += 64) {
    __syncthreads();   // tile k0 visible
    GCOMPUTE();
    __syncthreads();
    GWRITE(B);                              // LDS <- k0+32 (always valid)
    if (k0 + 64 < K) GLOAD(A, k0 + 64);     // A <- k0+64
    __syncthreads();   // tile k0+32 visible
    GCOMPUTE();
    __syncthreads();
    if (k0 + 64 < K) GWRITE(A);             // LDS <- k0+64
    if (k0 + 96 < K) GLOAD(B, k0 + 96);     // B <- k0+96
  }
#undef GLOAD
#undef GWRITE
#undef GCOMPUTE
#pragma unroll
  for (int fm = 0; fm < 4; fm++)
#pragma unroll
    for (int fn = 0; fn < 4; fn++)
#pragma unroll
      for (int rr = 0; rr < 4; rr++) {
        int row = m0 + wr * 64 + fm * 16 + b8 * 4 + rr;
        int col = n0 + wc * 64 + fn * 16 + mi;
        float v = acc[fm][fn][rr];
        size_t o = (size_t)row * N + col;
        if (Cph) {
          if (col < scale_cols) v *= 0.125f;
          uint16_t hv = f2bf(v);
          Cph[o] = hv;
          Cpl[o] = f2bf(v - __uint_as_float((uint32_t)hv << 16));
        } else {
          if (res) v += res[o];
          C[o] = v;
        }
      }
}

// ---------------- flash attention: QBLK=128, NO-MAX softmax, l via ones-MFMA, plane inputs ----------------
template <bool CAUSAL>
__global__ __launch_bounds__(256, 3) void k_fattn(
    const uint16_t* __restrict__ qhg, const uint16_t* __restrict__ qlg, int qs,
    const uint16_t* __restrict__ khg, const uint16_t* __restrict__ klg, int ks_, int khdiv,
    const uint16_t* __restrict__ vhg, const uint16_t* __restrict__ vlg, int nvrows,
    uint16_t* __restrict__ yhg, uint16_t* __restrict__ ylg) {
  __shared__ uint16_t Ksh[64][68], Ksl[64][68];
  __shared__ uint16_t Vsh[64][68], Vsl[64][68];
  __shared__ uint32_t Ps[4][32][36];
  const int h = blockIdx.y, b = blockIdx.z;
  const int qt = CAUSAL ? ((blockIdx.x + h + 2 * b) & 7) : blockIdx.x;
  const int tid = threadIdx.x, wv = tid >> 6, ln = tid & 63, mi = ln & 15, b8 = ln >> 4;
  const int koff = (h / khdiv) * 64;
  const uint16_t* kbh = khg + (size_t)b * T_ * ks_ + koff;
  const uint16_t* kbl = klg + (size_t)b * T_ * ks_ + koff;
  const uint16_t* vbh = vhg + ((size_t)b * nvrows + koff) * T_;
  const uint16_t* vbl = vlg + ((size_t)b * nvrows + koff) * T_;

  bf16x8 qh[2][2], ql[2][2];   // [u][k2]
#pragma unroll
  for (int u = 0; u < 2; u++)
#pragma unroll
    for (int k2 = 0; k2 < 2; k2++) {
      size_t o = (size_t)(b * T_ + qt * 128 + wv * 32 + u * 16 + mi) * qs + h * 64 + k2 * 32 + b8 * 8;
      qh[u][k2] = *(const bf16x8*)&qhg[o];
      ql[u][k2] = *(const bf16x8*)&qlg[o];
    }

  PK8 ONE_;
  ONE_.u[0] = 0x3F803F80u; ONE_.u[1] = 0x3F803F80u;
  ONE_.u[2] = 0x3F803F80u; ONE_.u[3] = 0x3F803F80u;
  const bf16x8 ones = ONE_.v;

  f32x4 lacc[2] = {};
  f32x4 o[2][4] = {};

  const int nkt = CAUSAL ? (2 * qt + 2) : (T_ / 64);
  for (int kt = 0; kt < nkt; kt++) {
    __syncthreads();
    {
      int rr = tid >> 2, cc = (tid & 3) * 16;
      size_t ko = (size_t)(kt * 64 + rr) * ks_ + cc;
      *(uint4*)&Ksh[rr][cc]     = *(const uint4*)&kbh[ko];
      *(uint4*)&Ksh[rr][cc + 8] = *(const uint4*)&kbh[ko + 8];
      *(uint4*)&Ksl[rr][cc]     = *(const uint4*)&kbl[ko];
      *(uint4*)&Ksl[rr][cc + 8] = *(const uint4*)&kbl[ko + 8];
      size_t vo = (size_t)rr * T_ + kt * 64 + cc;
      *(uint4*)&Vsh[rr][cc]     = *(const uint4*)&vbh[vo];
      *(uint4*)&Vsh[rr][cc + 8] = *(const uint4*)&vbh[vo + 8];
      *(uint4*)&Vsl[rr][cc]     = *(const uint4*)&vbl[vo];
      *(uint4*)&Vsl[rr][cc + 8] = *(const uint4*)&vbl[vo + 8];
    }
    __syncthreads();
#pragma unroll
    for (int s = 0; s < 2; s++) {
      bf16x8 kh[2][2], kl[2][2];  // [nf][k2]
#pragma unroll
      for (int nf = 0; nf < 2; nf++)
#pragma unroll
        for (int k2 = 0; k2 < 2; k2++) {
          int rrow = s * 32 + nf * 16 + mi, ccol = k2 * 32 + b8 * 8;
          kh[nf][k2] = *(const bf16x8*)&Ksh[rrow][ccol];
          kl[nf][k2] = *(const bf16x8*)&Ksl[rrow][ccol];
        }
      f32x4 a[2][2] = {};  // [u][nf]
#pragma unroll
      for (int u = 0; u < 2; u++)
#pragma unroll
        for (int nf = 0; nf < 2; nf++)
#pragma unroll
          for (int k2 = 0; k2 < 2; k2++) {
            a[u][nf] = MFMA_BF16(ql[u][k2], kh[nf][k2], a[u][nf], 0, 0, 0);
            a[u][nf] = MFMA_BF16(qh[u][k2], kl[nf][k2], a[u][nf], 0, 0, 0);
            a[u][nf] = MFMA_BF16(qh[u][k2], kh[nf][k2], a[u][nf], 0, 0, 0);
          }
      if (CAUSAL && kt >= 2 * qt) {
        int kg = kt * 64 + s * 32 + mi;
#pragma unroll
        for (int u = 0; u < 2; u++) {
          int qg = qt * 128 + wv * 32 + u * 16 + b8 * 4;
#pragma unroll
          for (int r = 0; r < 4; r++) {
            if (kg > qg + r)      a[u][0][r] = -1e30f;
            if (kg + 16 > qg + r) a[u][1][r] = -1e30f;
          }
        }
      }
#pragma unroll
      for (int u = 0; u < 2; u++) {
#pragma unroll
        for (int r = 0; r < 4; r++) {
          a[u][0][r] = __expf(a[u][0][r]);
          a[u][1][r] = __expf(a[u][1][r]);
        }
#pragma unroll
        for (int r = 0; r < 4; r++) {
          uint32_t Hw, Lw;
          asm("v_cvt_pk_bf16_f32 %0, %1, %2" : "=v"(Hw) : "v"(a[u][0][r]), "v"(a[u][1][r]));
          float h0 = __uint_as_float(Hw << 16);
          float h1 = __uint_as_float(Hw & 0xffff0000u);
          float r0 = a[u][0][r] - h0, r1 = a[u][1][r] - h1;
          asm("v_cvt_pk_bf16_f32 %0, %1, %2" : "=v"(Lw) : "v"(r0), "v"(r1));
          Ps[wv][u * 16 + b8 * 4 + r][mi]      = __builtin_amdgcn_perm(Hw, Lw, 0x05040100u);
          Ps[wv][u * 16 + b8 * 4 + r][16 + mi] = __builtin_amdgcn_perm(Hw, Lw, 0x07060302u);
        }
      }
      // PV (+ l row-sum via ones-MFMA on the matrix pipe)
      bf16x8 ph[2], pl[2];
#pragma unroll
      for (int u = 0; u < 2; u++) {
        const uint32_t* p = &Ps[wv][u * 16 + mi][b8 * 8];
        unpack8(*(const uint4*)p, *(const uint4*)(p + 4), ph[u], pl[u]);
      }
#pragma unroll
      for (int u = 0; u < 2; u++) {
        lacc[u] = MFMA_BF16(pl[u], ones, lacc[u], 0, 0, 0);
        lacc[u] = MFMA_BF16(ph[u], ones, lacc[u], 0, 0, 0);
      }
#pragma unroll
      for (int f = 0; f < 4; f++) {
        int rrow = f * 16 + mi, ccol = s * 32 + b8 * 8;
        bf16x8 vh = *(const bf16x8*)&Vsh[rrow][ccol];
        bf16x8 vl = *(const bf16x8*)&Vsl[rrow][ccol];
#pragma unroll
        for (int u = 0; u < 2; u++) {
          o[u][f] = MFMA_BF16(pl[u], vh, o[u][f], 0, 0, 0);
          o[u][f] = MFMA_BF16(ph[u], vl, o[u][f], 0, 0, 0);
          o[u][f] = MFMA_BF16(ph[u], vh, o[u][f], 0, 0, 0);
        }
      }
    }
  }
#pragma unroll
  for (int u = 0; u < 2; u++)
#pragma unroll
    for (int r = 0; r < 4; r++) {
      float inv = 1.0f / lacc[u][r];
      int row = qt * 128 + wv * 32 + u * 16 + b8 * 4 + r;
#pragma unroll
      for (int f = 0; f < 4; f++) {
        size_t idx = (size_t)(b * T_ + row) * D_ + h * 64 + f * 16 + mi;
        float v = o[u][f][r] * inv;
        uint16_t hv = f2bf(v);
        yhg[idx] = hv;
        ylg[idx] = f2bf(v - __uint_as_float((uint32_t)hv << 16));
      }
    }
}

__global__ __launch_bounds__(256) void k_bucket(const int* __restrict__ idx, int* __restrict__ cnt,
                                                int* __restrict__ lists) {
  int tok = blockIdx.x * 256 + threadIdx.x;
  int e = idx[tok];
  int p = atomicAdd(&cnt[e], 1);
  lists[e * NT + p] = tok;
}

// ---------------- MoE GEMM1: 64 x 128, BK=64, distance-2 reg-prefetch, expert->XCD confinement ----------------
__global__ __launch_bounds__(256) void k_moe1(const uint16_t* __restrict__ xmbf, const uint16_t* __restrict__ w1t,
                                              const float* __restrict__ b1, const int* __restrict__ cnt,
                                              const int* __restrict__ lists, uint16_t* __restrict__ hbf) {
  int bid = blockIdx.x;
  int e = bid & 7;
  int inner = bid >> 3;
  int n0 = (inner & 31) * 128;     // F/128 = 32 n-tiles
  int m0 = (inner >> 5) * 64;      // NT/64 = 64 m-rows
  int c = cnt[e];
  if (m0 >= c) return;
  __shared__ uint16_t As[64][72];
  __shared__ uint16_t Ws[128][72];
  __shared__ int toks[64];
  int tid = threadIdx.x, wv = tid >> 6, ln = tid & 63, mi = ln & 15, b8 = ln >> 4;
  if (tid < 64) toks[tid] = (m0 + tid < c) ? lists[e * NT + m0 + tid] : -1;
  __syncthreads();
  int ra = tid >> 2, ca = (tid & 3) * 16;
  int rw = tid >> 1, cw = (tid & 1) * 32;
  int tk = toks[ra];
  const uint16_t* asrc = (tk >= 0) ? (xmbf + (size_t)tk * D_ + ca) : nullptr;
  const uint16_t* wsrc = w1t + (size_t)e * F_ * D_ + (size_t)(n0 + rw) * D_ + cw;
  f32x4 acc[4][2] = {};
  uint4 a0A = make_uint4(0,0,0,0), a1A = make_uint4(0,0,0,0), w0A, w1A, w2A, w3A;
  uint4 a0B = make_uint4(0,0,0,0), a1B = make_uint4(0,0,0,0), w0B, w1B, w2B, w3B;

#define M1LOAD(S, k0) do {                                                     \
    if (asrc) { a0##S = *(const uint4*)(asrc + (k0)); a1##S = *(const uint4*)(asrc + (k0) + 8); } \
    w0##S = *(const uint4*)(wsrc + (k0));      w1##S = *(const uint4*)(wsrc + (k0) + 8);  \
    w2##S = *(const uint4*)(wsrc + (k0) + 16); w3##S = *(const uint4*)(wsrc + (k0) + 24); \
  } while (0)
#define M1WRITE(S) do {                                                        \
    *(uint4*)&As[ra][ca] = a0##S;       *(uint4*)&As[ra][ca + 8] = a1##S;      \
    *(uint4*)&Ws[rw][cw] = w0##S;       *(uint4*)&Ws[rw][cw + 8] = w1##S;      \
    *(uint4*)&Ws[rw][cw + 16] = w2##S;  *(uint4*)&Ws[rw][cw + 24] = w3##S;     \
  } while (0)
#define M1COMPUTE() do {                                                       \
    _Pragma("unroll")                                                          \
    for (int ks = 0; ks < 2; ks++) {                                           \
      bf16x8 a[4], bb[2];                                                      \
      _Pragma("unroll")                                                        \
      for (int fm = 0; fm < 4; fm++)                                           \
        a[fm] = *(const bf16x8*)&As[fm * 16 + mi][ks * 32 + b8 * 8];           \
      _Pragma("unroll")                                                        \
      for (int nf = 0; nf < 2; nf++)                                           \
        bb[nf] = *(const bf16x8*)&Ws[wv * 32 + nf * 16 + mi][ks * 32 + b8 * 8];\
      _Pragma("unroll")                                                        \
      for (int fm = 0; fm < 4; fm++)                                           \
        _Pragma("unroll")                                                      \
        for (int nf = 0; nf < 2; nf++)                                         \
          acc[fm][nf] = MFMA_BF16(a[fm], bb[nf], acc[fm][nf], 0, 0, 0);        \
    }                                                                          \
  } while (0)

  M1LOAD(A, 0);
  M1WRITE(A);
  M1LOAD(B, 64);
  for (int k0 = 0; k0 < D_; k0 += 128) {
    __syncthreads();
    M1COMPUTE();
    __syncthreads();
    M1WRITE(B);
    if (k0 + 128 < D_) M1LOAD(A, k0 + 128);
    __syncthreads();
    M1COMPUTE();
    __syncthreads();
    if (k0 + 128 < D_) M1WRITE(A);
    if (k0 + 192 < D_) M1LOAD(B, k0 + 192);
  }
#undef M1LOAD
#undef M1WRITE
#undef M1COMPUTE
#pragma unroll
  for (int fm = 0; fm < 4; fm++)
#pragma unroll
    for (int nf = 0; nf < 2; nf++)
#pragma unroll
      for (int rr = 0; rr < 4; rr++) {
        int rt = fm * 16 + b8 * 4 + rr;
        if (m0 + rt < c) {
          int tok = toks[rt];
          int col = n0 + wv * 32 + nf * 16 + mi;
          float v = acc[fm][nf][rr] + b1[e * F_ + col];
          v = v / (1.0f + expf(-v));
          hbf[(size_t)tok * F_ + col] = f2bf(v);
        }
      }
}

// ---------------- MoE GEMM2: 128 x 64 tile (acc[2][4]), BK=64, distance-2 reg-prefetch, XCD confinement ----------------
// Compute phase doubled (16 MFMA/wave per K-step) to extend prefetch flight past L3/HBM fill latency.
__global__ __launch_bounds__(256) void k_moe2(const uint16_t* __restrict__ hbf, const uint16_t* __restrict__ w2t,
                                              const float* __restrict__ b2, const float* __restrict__ x2,
                                              const float* __restrict__ sc, const int* __restrict__ cnt,
                                              const int* __restrict__ lists, float* __restrict__ out) {
  int bid = blockIdx.x;
  int e = bid & 7;
  int inner = bid >> 3;
  int n0 = (inner & 15) * 64;       // D/64 = 16 n-tiles
  int m0 = (inner >> 4) * 128;      // NT/128 = 32 m-tiles
  int c = cnt[e];
  if (m0 >= c) return;
  __shared__ uint16_t As[128][72];
  __shared__ uint16_t Ws[64][72];
  __shared__ int toks[128];
  int tid = threadIdx.x, wv = tid >> 6, ln = tid & 63, mi = ln & 15, b8 = ln >> 4;
  if (tid < 128) toks[tid] = (m0 + tid < c) ? lists[e * NT + m0 + tid] : -1;
  __syncthreads();
  int ra = tid >> 1, ca = (tid & 1) * 32;   // A: 2 thr/row, 32 elems each (4 uint4)
  int rw = tid >> 2, cw = (tid & 3) * 16;   // W: 4 thr/row, 16 elems each (2 uint4)
  int tk = toks[ra];
  const uint16_t* asrc = (tk >= 0) ? (hbf + (size_t)tk * F_ + ca) : nullptr;
  const uint16_t* wsrc = w2t + (size_t)e * D_ * F_ + (size_t)(n0 + rw) * F_ + cw;
  f32x4 acc[2][4] = {};
  uint4 a0A = make_uint4(0,0,0,0), a1A = make_uint4(0,0,0,0), a2A = make_uint4(0,0,0,0), a3A = make_uint4(0,0,0,0), w0A, w1A;
  uint4 a0B = make_uint4(0,0,0,0), a1B = make_uint4(0,0,0,0), a2B = make_uint4(0,0,0,0), a3B = make_uint4(0,0,0,0), w0B, w1B;

#define M2LOAD(S, k0) do {                                                     \
    if (asrc) {                                                                \
      a0##S = *(const uint4*)(asrc + (k0));      a1##S = *(const uint4*)(asrc + (k0) + 8);  \
      a2##S = *(const uint4*)(asrc + (k0) + 16); a3##S = *(const uint4*)(asrc + (k0) + 24); \
    }                                                                          \
    w0##S = *(const uint4*)(wsrc + (k0)); w1##S = *(const uint4*)(wsrc + (k0) + 8); \
  } while (0)
#define M2WRITE(S) do {                                                        \
    *(uint4*)&As[ra][ca] = a0##S;       *(uint4*)&As[ra][ca + 8] = a1##S;      \
    *(uint4*)&As[ra][ca + 16] = a2##S;  *(uint4*)&As[ra][ca + 24] = a3##S;     \
    *(uint4*)&Ws[rw][cw] = w0##S;       *(uint4*)&Ws[rw][cw + 8] = w1##S;      \
  } while (0)
#define M2COMPUTE() do {                                                       \
    _Pragma("unroll")                                                          \
    for (int ks = 0; ks < 2; ks++) {                                           \
      bf16x8 a[2], bb[4];                                                      \
      _Pragma("unroll")                                                        \
      for (int fm = 0; fm < 2; fm++)                                           \
        a[fm] = *(const bf16x8*)&As[wv * 32 + fm * 16 + mi][ks * 32 + b8 * 8]; \
      _Pragma("unroll")                                                        \
      for (int fn = 0; fn < 4; fn++)                                           \
        bb[fn] = *(const bf16x8*)&Ws[fn * 16 + mi][ks * 32 + b8 * 8];          \
      _Pragma("unroll")                                                        \
      for (int fm = 0; fm < 2; fm++)                                           \
        _Pragma("unroll")                                                      \
        for (int fn = 0; fn < 4; fn++)                                         \
          acc[fm][fn] = MFMA_BF16(a[fm], bb[fn], acc[fm][fn], 0, 0, 0);        \
    }                                                                          \
  } while (0)

  M2LOAD(A, 0);
  M2WRITE(A);
  M2LOAD(B, 64);
  for (int k0 = 0; k0 < F_; k0 += 128) {
    __syncthreads();
    M2COMPUTE();
    __syncthreads();
    M2WRITE(B);
    if (k0 + 128 < F_) M2LOAD(A, k0 + 128);
    __syncthreads();
    M2COMPUTE();
    __syncthreads();
    if (k0 + 128 < F_) M2WRITE(A);
    if (k0 + 192 < F_) M2LOAD(B, k0 + 192);
  }
#undef M2LOAD
#undef M2WRITE
#undef M2COMPUTE
#pragma unroll
  for (int fm = 0; fm < 2; fm++)
#pragma unroll
    for (int fn = 0; fn < 4; fn++)
#pragma unroll
      for (int rr = 0; rr < 4; rr++) {
        int rt = wv * 32 + fm * 16 + b8 * 4 + rr;
        if (m0 + rt < c) {
          int tok = toks[rt];
          int col = n0 + fn * 16 + mi;
          float v = acc[fm][fn][rr] + b2[e * D_ + col];
          out[(size_t)tok * D_ + col] = x2[(size_t)tok * D_ + col] + sc[tok] * v;
        }
      }
}

extern "C" void kernel_launch(void* const* d_in, const int* in_sizes, int n_in,
                              void* d_out, int out_size, void* d_ws, size_t ws_size,
                              hipStream_t stream) {
  const float* x       = (const float*)d_in[0];
  const float* k_ctx   = (const float*)d_in[1];
  const float* v_ctx   = (const float*)d_in[2];
  const float* sa_nw   = (const float*)d_in[3];
  const float* w_qkv   = (const float*)d_in[4];
  const float* sa_wout = (const float*)d_in[5];
  const float* ca_nw   = (const float*)d_in[6];
  const float* w_q     = (const float*)d_in[7];
  const float* ca_wout = (const float*)d_in[8];
  const float* moe_nw  = (const float*)d_in[9];
  const float* w_gate  = (const float*)d_in[10];
  const float* w1      = (const float*)d_in[11];
  const float* b1      = (const float*)d_in[12];
  const float* w2      = (const float*)d_in[13];
  const float* b2      = (const float*)d_in[14];
  float* out = (float*)d_out;
  (void)in_sizes; (void)n_in; (void)out_size; (void)ws_size;

  char* ws = (char*)d_ws;
  size_t off = 0;
  auto alloc = [&](size_t bytes) { char* p = ws + off; off += (bytes + 255) & ~(size_t)255; return p; };
  uint16_t* xnh   = (uint16_t*)alloc((size_t)NT * D_ * 2);
  uint16_t* xnl   = (uint16_t*)alloc((size_t)NT * D_ * 2);
  uint16_t* yh    = (uint16_t*)alloc((size_t)NT * D_ * 2);
  uint16_t* yl    = (uint16_t*)alloc((size_t)NT * D_ * 2);
  float*    x1    = (float*)alloc((size_t)NT * D_ * 4);
  uint16_t* qkvh  = (uint16_t*)alloc((size_t)NT * 3 * D_ * 2);   // 24 MB
  uint16_t* qkvl  = (uint16_t*)alloc((size_t)NT * 3 * D_ * 2);   // 24 MB
  float* x2 = (float*)qkvh;
  uint16_t* qch = qkvl;
  uint16_t* qcl = qkvl + (size_t)NT * D_;
  uint16_t* wqkvTh = (uint16_t*)alloc((size_t)D_ * 3 * D_ * 2);
  uint16_t* wqkvTl = (uint16_t*)alloc((size_t)D_ * 3 * D_ * 2);
  uint16_t* sawTh  = (uint16_t*)alloc((size_t)D_ * D_ * 2);
  uint16_t* sawTl  = (uint16_t*)alloc((size_t)D_ * D_ * 2);
  uint16_t* wqTh   = (uint16_t*)alloc((size_t)D_ * D_ * 2);
  uint16_t* wqTl   = (uint16_t*)alloc((size_t)D_ * D_ * 2);
  uint16_t* cawTh  = (uint16_t*)alloc((size_t)D_ * D_ * 2);
  uint16_t* cawTl  = (uint16_t*)alloc((size_t)D_ * D_ * 2);
  uint16_t* w1t   = (uint16_t*)alloc((size_t)E_ * D_ * F_ * 2);
  uint16_t* w2t   = (uint16_t*)alloc((size_t)E_ * D_ * F_ * 2);
  uint16_t* hbf   = (uint16_t*)alloc((size_t)NT * F_ * 2);   // 32 MB, MoE-phase only
  uint16_t* vth   = (uint16_t*)hbf;                                        // 8 MB
  uint16_t* vtl   = vth + (size_t)NT * D_;                                 // 8 MB
  uint16_t* kch   = (uint16_t*)((char*)hbf + (size_t)16 * 1024 * 1024);    // 2 MB
  uint16_t* kcl   = (uint16_t*)((char*)hbf + (size_t)18 * 1024 * 1024);    // 2 MB
  uint16_t* vcth  = (uint16_t*)((char*)hbf + (size_t)20 * 1024 * 1024);    // 2 MB
  uint16_t* vctl  = (uint16_t*)((char*)hbf + (size_t)22 * 1024 * 1024);    // 2 MB
  uint16_t* xmbf  = (uint16_t*)alloc((size_t)NT * D_ * 2);
  int*   idx   = (int*)alloc(NT * 4);
  float* scb   = (float*)alloc(NT * 4);
  int*   cnt   = (int*)alloc(256);
  int*   lists = (int*)alloc((size_t)E_ * NT * 4);

  // weight prep (merged launches)
  k_pack_all<<<dim3(32, 32, 6), 256, 0, stream>>>(w_qkv, sa_wout, w_q, ca_wout,
                                                  wqkvTh, wqkvTl, sawTh, sawTl,
                                                  wqTh, wqTl, cawTh, cawTl);
  k_bf_t2<<<dim3(1024, 1, 16), 256, 0, stream>>>(w1, w2, w1t, w2t);
  // cross-attn K/V prep (planes)
  k_packf2<<<(B_ * T_ * 256) / 1024, 256, 0, stream>>>(k_ctx, kch, kcl);
  k_tf32<<<dim3(T_ / 32, 256 / 32, B_), 256, 0, stream>>>(v_ctx, vcth, vctl);

  // self-attention block
  k_rms<<<NT, 256, 0, stream>>>(x, sa_nw, xnh, xnl, nullptr, nullptr, nullptr);
  k_gemm_split<<<dim3(3 * D_ / GBN, NT / GBM), 256, 0, stream>>>(xnh, xnl, wqkvTh, wqkvTl, nullptr, nullptr, qkvh, qkvl, 1024, NT, 3 * D_, D_);
  k_t16<<<dim3(T_ / 64, D_ / 64, B_), 256, 0, stream>>>(qkvh, qkvl, vth, vtl);
  k_fattn<true><<<dim3(T_ / 128, H_, B_), 256, 0, stream>>>(qkvh, qkvl, 3072, qkvh + 1024, qkvl + 1024, 3072, 1, vth, vtl, 1024, yh, yl);
  k_gemm_split<<<dim3(D_ / GBN, NT / GBM), 256, 0, stream>>>(yh, yl, sawTh, sawTl, x1, x, nullptr, nullptr, 0, NT, D_, D_);

  // cross-attention block (GQA)
  k_rms<<<NT, 256, 0, stream>>>(x1, ca_nw, xnh, xnl, nullptr, nullptr, nullptr);
  k_gemm_split<<<dim3(D_ / GBN, NT / GBM), 256, 0, stream>>>(xnh, xnl, wqTh, wqTl, nullptr, nullptr, qch, qcl, 1024, NT, D_, D_);
  k_fattn<false><<<dim3(T_ / 128, H_, B_), 256, 0, stream>>>(qch, qcl, 1024, kch, kcl, 256, 4, vcth, vctl, 256, yh, yl);
  k_gemm_split<<<dim3(D_ / GBN, NT / GBM), 256, 0, stream>>>(yh, yl, cawTh, cawTl, x2, x1, nullptr, nullptr, 0, NT, D_, D_);

  // MoE (gate fused into RMSNorm); expert->XCD confined 1D grids
  k_rms<<<NT, 256, 0, stream>>>(x2, moe_nw, xmbf, nullptr, w_gate, idx, scb);
  hipMemsetAsync(cnt, 0, 32, stream);
  k_bucket<<<NT / 256, 256, 0, stream>>>(idx, cnt, lists);
  k_moe1<<<dim3(8 * (F_ / 128) * (NT / 64)), 256, 0, stream>>>(xmbf, w1t, b1, cnt, lists, hbf);
  k_moe2<<<dim3(8 * (D_ / 64) * (NT / 128)), 256, 0, stream>>>(hbf, w2t, b2, x2, scb, cnt, lists, out);
}

// Round 27
// 692.904 us; speedup vs baseline: 1.0271x; 1.0015x over previous
//
#include <hip/hip_runtime.h>
#include <hip/hip_bf16.h>
#include <stdint.h>

#define B_  4
#define T_  1024
#define D_  1024
#define H_  16
#define DH  64
#define F_  4096
#define E_  8
#define NT  (B_*T_)          // 4096 tokens

typedef float f32x4 __attribute__((ext_vector_type(4)));
typedef short bf16x8 __attribute__((ext_vector_type(8)));
#define MFMA_BF16 __builtin_amdgcn_mfma_f32_16x16x32_bf16

union PK8 { uint32_t u[4]; bf16x8 v; };

// ---- bf16 helpers: RNE round, split f32 -> hi/lo bf16 ----
static __device__ __forceinline__ uint16_t f2bf(float f) {
  uint32_t u = __float_as_uint(f);
  u += 0x7FFFu + ((u >> 16) & 1u);
  return (uint16_t)(u >> 16);
}
// unpack 8 packed u32 -> hi / lo bf16x8 (used only for P tiles in fattn)
static __device__ __forceinline__ void unpack8(const uint4 p0, const uint4 p1, bf16x8 &hi, bf16x8 &lo) {
  PK8 H, L;
  H.u[0] = __builtin_amdgcn_perm(p0.y, p0.x, 0x07060302u);
  L.u[0] = __builtin_amdgcn_perm(p0.y, p0.x, 0x05040100u);
  H.u[1] = __builtin_amdgcn_perm(p0.w, p0.z, 0x07060302u);
  L.u[1] = __builtin_amdgcn_perm(p0.w, p0.z, 0x05040100u);
  H.u[2] = __builtin_amdgcn_perm(p1.y, p1.x, 0x07060302u);
  L.u[2] = __builtin_amdgcn_perm(p1.y, p1.x, 0x05040100u);
  H.u[3] = __builtin_amdgcn_perm(p1.w, p1.z, 0x07060302u);
  L.u[3] = __builtin_amdgcn_perm(p1.w, p1.z, 0x05040100u);
  hi = H.v; lo = L.v;
}

// ---------------- merged dense-weight prep v2: 64x64 tiles, uint4 stores ----------------
// transpose [K=1024][N] -> [N][1024] hi/lo planes
__global__ __launch_bounds__(256) void k_pack_all(
    const float* __restrict__ wqkv, const float* __restrict__ saw,
    const float* __restrict__ wq,   const float* __restrict__ caw,
    uint16_t* __restrict__ qkvTh, uint16_t* __restrict__ qkvTl,
    uint16_t* __restrict__ sawTh, uint16_t* __restrict__ sawTl,
    uint16_t* __restrict__ wqTh,  uint16_t* __restrict__ wqTl,
    uint16_t* __restrict__ cawTh, uint16_t* __restrict__ cawTl) {
  __shared__ float t[64][65];
  int z = blockIdx.z;
  const float* in; uint16_t *oh, *ol; int N, nbase;
  if (z < 3)       { in = wqkv; oh = qkvTh; ol = qkvTl; N = 3072; nbase = z * 1024; }
  else if (z == 3) { in = saw;  oh = sawTh; ol = sawTl; N = 1024; nbase = 0; }
  else if (z == 4) { in = wq;   oh = wqTh;  ol = wqTl;  N = 1024; nbase = 0; }
  else             { in = caw;  oh = cawTh; ol = cawTl; N = 1024; nbase = 0; }
  int n0 = nbase + blockIdx.x * 64, k0 = blockIdx.y * 64;
  int tr = threadIdx.x >> 4;
  int tc = (threadIdx.x & 15) * 4;
#pragma unroll
  for (int i = 0; i < 64; i += 16) {
    float4 v = *(const float4*)&in[(size_t)(k0 + tr + i) * N + n0 + tc];
    t[tr + i][tc] = v.x; t[tr + i][tc + 1] = v.y; t[tr + i][tc + 2] = v.z; t[tr + i][tc + 3] = v.w;
  }
  __syncthreads();
  int wr_ = threadIdx.x >> 3;       // 0..31
  int wc_ = (threadIdx.x & 7) * 8;  // 0..56
#pragma unroll
  for (int i = 0; i < 64; i += 32) {
    int n = wr_ + i;
    uint16_t bh[8], bl[8];
#pragma unroll
    for (int j = 0; j < 8; j++) {
      float v = t[wc_ + j][n];
      bh[j] = f2bf(v);
      bl[j] = f2bf(v - __uint_as_float((uint32_t)bh[j] << 16));
    }
    uint4 ph, pl;
    ph.x = ((uint32_t)bh[1] << 16) | bh[0];
    ph.y = ((uint32_t)bh[3] << 16) | bh[2];
    ph.z = ((uint32_t)bh[5] << 16) | bh[4];
    ph.w = ((uint32_t)bh[7] << 16) | bh[6];
    pl.x = ((uint32_t)bl[1] << 16) | bl[0];
    pl.y = ((uint32_t)bl[3] << 16) | bl[2];
    pl.z = ((uint32_t)bl[5] << 16) | bl[4];
    pl.w = ((uint32_t)bl[7] << 16) | bl[6];
    size_t o = (size_t)(n0 + n) * 1024 + k0 + wc_;
    *(uint4*)&oh[o] = ph;
    *(uint4*)&ol[o] = pl;
  }
}

// merged MoE weight prep v2: w1 [D][F] and w2 [F][D] -> transposed bf16; uint4 stores; z = which*8 + e
__global__ __launch_bounds__(256) void k_bf_t2(const float* __restrict__ w1, const float* __restrict__ w2,
                                               uint16_t* __restrict__ w1t, uint16_t* __restrict__ w2t) {
  __shared__ float t[64][65];
  int z = blockIdx.z;
  int which = z >> 3, e = z & 7;
  const float* in = which ? w2 : w1;
  uint16_t* out = which ? w2t : w1t;
  int K = which ? F_ : D_, N = which ? D_ : F_;
  const size_t mo = (size_t)e * (size_t)D_ * F_;
  in += mo; out += mo;
  int tile = blockIdx.x;
  int n0, k0;
  if (which) { n0 = (tile & 15) * 64; k0 = (tile >> 4) * 64; }
  else       { n0 = (tile & 63) * 64; k0 = (tile >> 6) * 64; }
  int tr = threadIdx.x >> 4;
  int tc = (threadIdx.x & 15) * 4;
#pragma unroll
  for (int i = 0; i < 64; i += 16) {
    float4 v = *(const float4*)&in[(size_t)(k0 + tr + i) * N + n0 + tc];
    t[tr + i][tc] = v.x; t[tr + i][tc + 1] = v.y; t[tr + i][tc + 2] = v.z; t[tr + i][tc + 3] = v.w;
  }
  __syncthreads();
  int wr_ = threadIdx.x >> 3;       // 0..31
  int wc_ = (threadIdx.x & 7) * 8;  // 0..56
#pragma unroll
  for (int i = 0; i < 64; i += 32) {
    int n = wr_ + i;
    uint16_t b[8];
#pragma unroll
    for (int j = 0; j < 8; j++) b[j] = f2bf(t[wc_ + j][n]);
    uint4 pv;
    pv.x = ((uint32_t)b[1] << 16) | b[0];
    pv.y = ((uint32_t)b[3] << 16) | b[2];
    pv.z = ((uint32_t)b[5] << 16) | b[4];
    pv.w = ((uint32_t)b[7] << 16) | b[6];
    *(uint4*)&out[(size_t)(n0 + n) * K + k0 + wc_] = pv;
  }
}

// u16 plane transpose of v-region of qkv planes: [b][t][2048+c] -> vt[(b*1024+c)][t]
__global__ __launch_bounds__(256) void k_t16(const uint16_t* __restrict__ inh, const uint16_t* __restrict__ inl,
                                             uint16_t* __restrict__ outh, uint16_t* __restrict__ outl) {
  __shared__ uint16_t th[64][68], tl[64][68];
  int b = blockIdx.z, t0 = blockIdx.x * 64, c0 = blockIdx.y * 64;
  int tr = threadIdx.x >> 4;
  int tc = (threadIdx.x & 15) * 4;
#pragma unroll
  for (int i = 0; i < 64; i += 16) {
    size_t src = (size_t)(b * T_ + t0 + tr + i) * 3072 + 2048 + c0 + tc;
    *(uint2*)&th[tr + i][tc] = *(const uint2*)&inh[src];
    *(uint2*)&tl[tr + i][tc] = *(const uint2*)&inl[src];
  }
  __syncthreads();
#pragma unroll
  for (int i = 0; i < 64; i += 16) {
    int n = tr + i;
    size_t dst = (size_t)(b * 1024 + c0 + n) * T_ + t0 + tc;
    uint2 ph, pl;
    ph.x = ((uint32_t)th[tc + 1][n] << 16) | th[tc][n];
    ph.y = ((uint32_t)th[tc + 3][n] << 16) | th[tc + 2][n];
    pl.x = ((uint32_t)tl[tc + 1][n] << 16) | tl[tc][n];
    pl.y = ((uint32_t)tl[tc + 3][n] << 16) | tl[tc + 2][n];
    *(uint2*)&outh[dst] = ph;
    *(uint2*)&outl[dst] = pl;
  }
}

// elementwise split f32 -> hi/lo planes
__global__ __launch_bounds__(256) void k_packf2(const float* __restrict__ in,
                                                uint16_t* __restrict__ oh, uint16_t* __restrict__ ol) {
  int i = (blockIdx.x * 256 + threadIdx.x) * 4;
  float4 v = *(const float4*)&in[i];
  uint16_t h0 = f2bf(v.x), h1 = f2bf(v.y), h2 = f2bf(v.z), h3 = f2bf(v.w);
  uint2 ph, pl;
  ph.x = ((uint32_t)h1 << 16) | h0;
  ph.y = ((uint32_t)h3 << 16) | h2;
  pl.x = ((uint32_t)f2bf(v.y - __uint_as_float((uint32_t)h1 << 16)) << 16) |
         f2bf(v.x - __uint_as_float((uint32_t)h0 << 16));
  pl.y = ((uint32_t)f2bf(v.w - __uint_as_float((uint32_t)h3 << 16)) << 16) |
         f2bf(v.z - __uint_as_float((uint32_t)h2 << 16));
  *(uint2*)&oh[i] = ph;
  *(uint2*)&ol[i] = pl;
}

// transpose+split: v_ctx f32 [b][t][gc] (gc<256) -> planes [(b*256+gc)][t]
__global__ __launch_bounds__(256) void k_tf32(const float* __restrict__ in,
                                              uint16_t* __restrict__ oh, uint16_t* __restrict__ ol) {
  __shared__ float t[32][33];
  int b = blockIdx.z, t0 = blockIdx.x * 32, c0 = blockIdx.y * 32;
  int tx = threadIdx.x & 31, ty = threadIdx.x >> 5;
#pragma unroll
  for (int i = 0; i < 32; i += 8)
    t[ty + i][tx] = in[(size_t)(b * T_ + t0 + ty + i) * 256 + c0 + tx];
  __syncthreads();
#pragma unroll
  for (int i = 0; i < 32; i += 8) {
    float v = t[tx][ty + i];
    uint16_t h = f2bf(v);
    size_t o = (size_t)(b * 256 + c0 + ty + i) * T_ + t0 + tx;
    oh[o] = h;
    ol[o] = f2bf(v - __uint_as_float((uint32_t)h << 16));
  }
}

// ---------------- RMSNorm (fp32 exact): hi/lo planes; optional fused MoE gate ----------------
__global__ __launch_bounds__(256) void k_rms(const float* __restrict__ x, const float* __restrict__ w,
                                             uint16_t* __restrict__ oh, uint16_t* __restrict__ ol,
                                             const float* __restrict__ wg, int* __restrict__ idxp,
                                             float* __restrict__ scb) {
  int row = blockIdx.x;
  const float* xr = x + (size_t)row * D_;
  int t = threadIdx.x;
  float4 xv = *(const float4*)&xr[t * 4];
  float s = xv.x * xv.x + xv.y * xv.y + xv.z * xv.z + xv.w * xv.w;
#pragma unroll
  for (int o = 32; o; o >>= 1) s += __shfl_xor(s, o, 64);
  __shared__ float ps[4];
  __shared__ float ga[4][8];
  if ((t & 63) == 0) ps[t >> 6] = s;
  __syncthreads();
  s = ps[0] + ps[1] + ps[2] + ps[3];
  float sc = 1.0f / sqrtf(s * (1.0f / (float)D_) + 1e-6f);
  float4 wv = *(const float4*)&w[t * 4];
  float o0 = xv.x * sc * wv.x, o1 = xv.y * sc * wv.y, o2 = xv.z * sc * wv.z, o3 = xv.w * sc * wv.w;
  uint16_t h0 = f2bf(o0), h1 = f2bf(o1), h2 = f2bf(o2), h3 = f2bf(o3);
  if (oh) {
    uint2 ph;
    ph.x = ((uint32_t)h1 << 16) | h0;
    ph.y = ((uint32_t)h3 << 16) | h2;
    *(uint2*)&oh[(size_t)row * D_ + t * 4] = ph;
  }
  if (ol) {
    uint16_t l0 = f2bf(o0 - __uint_as_float((uint32_t)h0 << 16));
    uint16_t l1 = f2bf(o1 - __uint_as_float((uint32_t)h1 << 16));
    uint16_t l2 = f2bf(o2 - __uint_as_float((uint32_t)h2 << 16));
    uint16_t l3 = f2bf(o3 - __uint_as_float((uint32_t)h3 << 16));
    uint2 pl;
    pl.x = ((uint32_t)l1 << 16) | l0;
    pl.y = ((uint32_t)l3 << 16) | l2;
    *(uint2*)&ol[(size_t)row * D_ + t * 4] = pl;
  }
  if (wg) {
    float a[8] = {};
    float ov[4] = {o0, o1, o2, o3};
#pragma unroll
    for (int j = 0; j < 4; j++) {
      const float* wr = &wg[(size_t)(t * 4 + j) * 8];
      float4 wa = *(const float4*)wr, wb = *(const float4*)(wr + 4);
      float v = ov[j];
      a[0] += v * wa.x; a[1] += v * wa.y; a[2] += v * wa.z; a[3] += v * wa.w;
      a[4] += v * wb.x; a[5] += v * wb.y; a[6] += v * wb.z; a[7] += v * wb.w;
    }
#pragma unroll
    for (int e = 0; e < 8; e++)
#pragma unroll
      for (int o = 32; o; o >>= 1) a[e] += __shfl_xor(a[e], o, 64);
    if ((t & 63) == 0)
#pragma unroll
      for (int e = 0; e < 8; e++) ga[t >> 6][e] = a[e];
    __syncthreads();
    if (t == 0) {
      float g[8];
#pragma unroll
      for (int e = 0; e < 8; e++) g[e] = ga[0][e] + ga[1][e] + ga[2][e] + ga[3][e];
      int bi = 0; float bv = g[0];
#pragma unroll
      for (int e = 1; e < 8; e++) if (g[e] > bv) { bv = g[e]; bi = e; }
      float se = 0.f;
#pragma unroll
      for (int e = 0; e < 8; e++) se += expf(g[e] - bv);
      idxp[row] = bi;
      scb[row] = 1.0f / se;
    }
  }
}

// ---------------- split-bf16 GEMM v13: 128x128 register-blocked tile (fm=fn=4), 3-MFMA split ----------------
#define GBM 128
#define GBN 128
__global__ __launch_bounds__(256) void k_gemm_split(const uint16_t* __restrict__ Ahg, const uint16_t* __restrict__ Alg,
                                                    const uint16_t* __restrict__ Whg, const uint16_t* __restrict__ Wlg,
                                                    float* __restrict__ C, const float* __restrict__ res,
                                                    uint16_t* __restrict__ Cph, uint16_t* __restrict__ Cpl,
                                                    int scale_cols, int M, int N, int K) {
  __shared__ uint16_t Ah[GBM][32], Al[GBM][32];
  __shared__ uint16_t Wh[GBN][32], Wl[GBN][32];
  int m0 = blockIdx.y * GBM, n0 = blockIdx.x * GBN;
  int tid = threadIdx.x, wv = tid >> 6, ln = tid & 63, mi = ln & 15, b8 = ln >> 4;
  const int wr = wv >> 1, wc = wv & 1;   // 2x2 wave grid, each wave 64x64 output
  int ra = tid >> 1, qa = tid & 1;
  const int cs0 = qa * 2 + ((ra >> 1) & 1);
  const int cs1 = cs0 ^ 1;
  const int sa0 = cs0 * 8;
  const int sa1 = cs1 * 8;
  const int go0 = (cs0 ^ (ra & 3)) * 8;
  const int go1 = (cs1 ^ (ra & 3)) * 8;
  const uint16_t* pAh0 = Ahg + (size_t)(m0 + ra) * K + go0;
  const uint16_t* pAh1 = Ahg + (size_t)(m0 + ra) * K + go1;
  const uint16_t* pAl0 = Alg + (size_t)(m0 + ra) * K + go0;
  const uint16_t* pAl1 = Alg + (size_t)(m0 + ra) * K + go1;
  const uint16_t* pWh0 = Whg + (size_t)(n0 + ra) * K + go0;
  const uint16_t* pWh1 = Whg + (size_t)(n0 + ra) * K + go1;
  const uint16_t* pWl0 = Wlg + (size_t)(n0 + ra) * K + go0;
  const uint16_t* pWl1 = Wlg + (size_t)(n0 + ra) * K + go1;
  const int ch8 = (b8 ^ (mi & 3)) * 8;
  f32x4 acc[4][4] = {};
  uint4 ah0A, ah1A, al0A, al1A, wh0A, wh1A, wl0A, wl1A;
  uint4 ah0B, ah1B, al0B, al1B, wh0B, wh1B, wl0B, wl1B;

#define GLOAD(S, k0) do {                                                      \
    ah0##S = *(const uint4*)(pAh0 + (k0));                                     \
    ah1##S = *(const uint4*)(pAh1 + (k0));                                     \
    al0##S = *(const uint4*)(pAl0 + (k0));                                     \
    al1##S = *(const uint4*)(pAl1 + (k0));                                     \
    wh0##S = *(const uint4*)(pWh0 + (k0));                                     \
    wh1##S = *(const uint4*)(pWh1 + (k0));                                     \
    wl0##S = *(const uint4*)(pWl0 + (k0));                                     \
    wl1##S = *(const uint4*)(pWl1 + (k0));                                     \
  } while (0)
#define GWRITE(S) do {                                                         \
    *(uint4*)&Ah[ra][sa0] = ah0##S; *(uint4*)&Ah[ra][sa1] = ah1##S;            \
    *(uint4*)&Al[ra][sa0] = al0##S; *(uint4*)&Al[ra][sa1] = al1##S;            \
    *(uint4*)&Wh[ra][sa0] = wh0##S; *(uint4*)&Wh[ra][sa1] = wh1##S;            \
    *(uint4*)&Wl[ra][sa0] = wl0##S; *(uint4*)&Wl[ra][sa1] = wl1##S;            \
  } while (0)
#define GCOMPUTE() do {                                                        \
    bf16x8 xah[4], xal[4], xbh[4], xbl[4];                                     \
    _Pragma("unroll")                                                          \
    for (int fm = 0; fm < 4; fm++) {                                           \
      xah[fm] = *(const bf16x8*)&Ah[wr * 64 + fm * 16 + mi][ch8];              \
      xal[fm] = *(const bf16x8*)&Al[wr * 64 + fm * 16 + mi][ch8];              \
    }                                                                          \
    _Pragma("unroll")                                                          \
    for (int fn = 0; fn < 4; fn++) {                                           \
      xbh[fn] = *(const bf16x8*)&Wh[wc * 64 + fn * 16 + mi][ch8];              \
      xbl[fn] = *(const bf16x8*)&Wl[wc * 64 + fn * 16 + mi][ch8];              \
    }                                                                          \
    _Pragma("unroll")                                                          \
    for (int fm = 0; fm < 4; fm++)                                             \
      _Pragma("unroll")                                                        \
      for (int fn = 0; fn < 4; fn++) {                                         \
        acc[fm][fn] = MFMA_BF16(xal[fm], xbh[fn], acc[fm][fn], 0, 0, 0);       \
        acc[fm][fn] = MFMA_BF16(xah[fm], xbl[fn], acc[fm][fn], 0, 0, 0);       \
        acc[fm][fn] = MFMA_BF16(xah[fm], xbh[fn], acc[fm][fn], 0, 0, 0);       \
      }                                                                        \
  } while (0)

  GLOAD(A, 0);
  GWRITE(A);           // LDS <- tile 0
  GLOAD(B, 32);        // B <- tile 1
  for (int k0 = 0; k0 < K; k0 += 64) {
    __syncthreads();   // tile k0 visible
    GCOMPUTE();
    __syncthreads();
    GWRITE(B);                              // LDS <- k0+32 (always valid)
    if (k0 + 64 < K) GLOAD(A, k0 + 64);     // A <- k0+64
    __syncthreads();   // tile k0+32 visible
    GCOMPUTE();
    __syncthreads();
    if (k0 + 64 < K) GWRITE(A);             // LDS <- k0+64
    if (k0 + 96 < K) GLOAD(B, k0 + 96);     // B <- k0+96
  }
#undef GLOAD
#undef GWRITE
#undef GCOMPUTE
#pragma unroll
  for (int fm = 0; fm < 4; fm++)
#pragma unroll
    for (int fn = 0; fn < 4; fn++)
#pragma unroll
      for (int rr = 0; rr < 4; rr++) {
        int row = m0 + wr * 64 + fm * 16 + b8 * 4 + rr;
        int col = n0 + wc * 64 + fn * 16 + mi;
        float v = acc[fm][fn][rr];
        size_t o = (size_t)row * N + col;
        if (Cph) {
          if (col < scale_cols) v *= 0.125f;
          uint16_t hv = f2bf(v);
          Cph[o] = hv;
          Cpl[o] = f2bf(v - __uint_as_float((uint32_t)hv << 16));
        } else {
          if (res) v += res[o];
          C[o] = v;
        }
      }
}

// ---------------- flash attention: QBLK=128, NO-MAX softmax, l via ones-MFMA, plane inputs ----------------
template <bool CAUSAL>
__global__ __launch_bounds__(256, 3) void k_fattn(
    const uint16_t* __restrict__ qhg, const uint16_t* __restrict__ qlg, int qs,
    const uint16_t* __restrict__ khg, const uint16_t* __restrict__ klg, int ks_, int khdiv,
    const uint16_t* __restrict__ vhg, const uint16_t* __restrict__ vlg, int nvrows,
    uint16_t* __restrict__ yhg, uint16_t* __restrict__ ylg) {
  __shared__ uint16_t Ksh[64][68], Ksl[64][68];
  __shared__ uint16_t Vsh[64][68], Vsl[64][68];
  __shared__ uint32_t Ps[4][32][36];
  const int h = blockIdx.y, b = blockIdx.z;
  const int qt = CAUSAL ? ((blockIdx.x + h + 2 * b) & 7) : blockIdx.x;
  const int tid = threadIdx.x, wv = tid >> 6, ln = tid & 63, mi = ln & 15, b8 = ln >> 4;
  const int koff = (h / khdiv) * 64;
  const uint16_t* kbh = khg + (size_t)b * T_ * ks_ + koff;
  const uint16_t* kbl = klg + (size_t)b * T_ * ks_ + koff;
  const uint16_t* vbh = vhg + ((size_t)b * nvrows + koff) * T_;
  const uint16_t* vbl = vlg + ((size_t)b * nvrows + koff) * T_;

  bf16x8 qh[2][2], ql[2][2];   // [u][k2]
#pragma unroll
  for (int u = 0; u < 2; u++)
#pragma unroll
    for (int k2 = 0; k2 < 2; k2++) {
      size_t o = (size_t)(b * T_ + qt * 128 + wv * 32 + u * 16 + mi) * qs + h * 64 + k2 * 32 + b8 * 8;
      qh[u][k2] = *(const bf16x8*)&qhg[o];
      ql[u][k2] = *(const bf16x8*)&qlg[o];
    }

  PK8 ONE_;
  ONE_.u[0] = 0x3F803F80u; ONE_.u[1] = 0x3F803F80u;
  ONE_.u[2] = 0x3F803F80u; ONE_.u[3] = 0x3F803F80u;
  const bf16x8 ones = ONE_.v;

  f32x4 lacc[2] = {};
  f32x4 o[2][4] = {};

  const int nkt = CAUSAL ? (2 * qt + 2) : (T_ / 64);
  for (int kt = 0; kt < nkt; kt++) {
    __syncthreads();
    {
      int rr = tid >> 2, cc = (tid & 3) * 16;
      size_t ko = (size_t)(kt * 64 + rr) * ks_ + cc;
      *(uint4*)&Ksh[rr][cc]     = *(const uint4*)&kbh[ko];
      *(uint4*)&Ksh[rr][cc + 8] = *(const uint4*)&kbh[ko + 8];
      *(uint4*)&Ksl[rr][cc]     = *(const uint4*)&kbl[ko];
      *(uint4*)&Ksl[rr][cc + 8] = *(const uint4*)&kbl[ko + 8];
      size_t vo = (size_t)rr * T_ + kt * 64 + cc;
      *(uint4*)&Vsh[rr][cc]     = *(const uint4*)&vbh[vo];
      *(uint4*)&Vsh[rr][cc + 8] = *(const uint4*)&vbh[vo + 8];
      *(uint4*)&Vsl[rr][cc]     = *(const uint4*)&vbl[vo];
      *(uint4*)&Vsl[rr][cc + 8] = *(const uint4*)&vbl[vo + 8];
    }
    __syncthreads();
#pragma unroll
    for (int s = 0; s < 2; s++) {
      bf16x8 kh[2][2], kl[2][2];  // [nf][k2]
#pragma unroll
      for (int nf = 0; nf < 2; nf++)
#pragma unroll
        for (int k2 = 0; k2 < 2; k2++) {
          int rrow = s * 32 + nf * 16 + mi, ccol = k2 * 32 + b8 * 8;
          kh[nf][k2] = *(const bf16x8*)&Ksh[rrow][ccol];
          kl[nf][k2] = *(const bf16x8*)&Ksl[rrow][ccol];
        }
      f32x4 a[2][2] = {};  // [u][nf]
#pragma unroll
      for (int u = 0; u < 2; u++)
#pragma unroll
        for (int nf = 0; nf < 2; nf++)
#pragma unroll
          for (int k2 = 0; k2 < 2; k2++) {
            a[u][nf] = MFMA_BF16(ql[u][k2], kh[nf][k2], a[u][nf], 0, 0, 0);
            a[u][nf] = MFMA_BF16(qh[u][k2], kl[nf][k2], a[u][nf], 0, 0, 0);
            a[u][nf] = MFMA_BF16(qh[u][k2], kh[nf][k2], a[u][nf], 0, 0, 0);
          }
      if (CAUSAL && kt >= 2 * qt) {
        int kg = kt * 64 + s * 32 + mi;
#pragma unroll
        for (int u = 0; u < 2; u++) {
          int qg = qt * 128 + wv * 32 + u * 16 + b8 * 4;
#pragma unroll
          for (int r = 0; r < 4; r++) {
            if (kg > qg + r)      a[u][0][r] = -1e30f;
            if (kg + 16 > qg + r) a[u][1][r] = -1e30f;
          }
        }
      }
#pragma unroll
      for (int u = 0; u < 2; u++) {
#pragma unroll
        for (int r = 0; r < 4; r++) {
          a[u][0][r] = __expf(a[u][0][r]);
          a[u][1][r] = __expf(a[u][1][r]);
        }
#pragma unroll
        for (int r = 0; r < 4; r++) {
          uint32_t Hw, Lw;
          asm("v_cvt_pk_bf16_f32 %0, %1, %2" : "=v"(Hw) : "v"(a[u][0][r]), "v"(a[u][1][r]));
          float h0 = __uint_as_float(Hw << 16);
          float h1 = __uint_as_float(Hw & 0xffff0000u);
          float r0 = a[u][0][r] - h0, r1 = a[u][1][r] - h1;
          asm("v_cvt_pk_bf16_f32 %0, %1, %2" : "=v"(Lw) : "v"(r0), "v"(r1));
          Ps[wv][u * 16 + b8 * 4 + r][mi]      = __builtin_amdgcn_perm(Hw, Lw, 0x05040100u);
          Ps[wv][u * 16 + b8 * 4 + r][16 + mi] = __builtin_amdgcn_perm(Hw, Lw, 0x07060302u);
        }
      }
      // PV (+ l row-sum via ones-MFMA on the matrix pipe)
      bf16x8 ph[2], pl[2];
#pragma unroll
      for (int u = 0; u < 2; u++) {
        const uint32_t* p = &Ps[wv][u * 16 + mi][b8 * 8];
        unpack8(*(const uint4*)p, *(const uint4*)(p + 4), ph[u], pl[u]);
      }
#pragma unroll
      for (int u = 0; u < 2; u++) {
        lacc[u] = MFMA_BF16(pl[u], ones, lacc[u], 0, 0, 0);
        lacc[u] = MFMA_BF16(ph[u], ones, lacc[u], 0, 0, 0);
      }
#pragma unroll
      for (int f = 0; f < 4; f++) {
        int rrow = f * 16 + mi, ccol = s * 32 + b8 * 8;
        bf16x8 vh = *(const bf16x8*)&Vsh[rrow][ccol];
        bf16x8 vl = *(const bf16x8*)&Vsl[rrow][ccol];
#pragma unroll
        for (int u = 0; u < 2; u++) {
          o[u][f] = MFMA_BF16(pl[u], vh, o[u][f], 0, 0, 0);
          o[u][f] = MFMA_BF16(ph[u], vl, o[u][f], 0, 0, 0);
          o[u][f] = MFMA_BF16(ph[u], vh, o[u][f], 0, 0, 0);
        }
      }
    }
  }
#pragma unroll
  for (int u = 0; u < 2; u++)
#pragma unroll
    for (int r = 0; r < 4; r++) {
      float inv = 1.0f / lacc[u][r];
      int row = qt * 128 + wv * 32 + u * 16 + b8 * 4 + r;
#pragma unroll
      for (int f = 0; f < 4; f++) {
        size_t idx = (size_t)(b * T_ + row) * D_ + h * 64 + f * 16 + mi;
        float v = o[u][f][r] * inv;
        uint16_t hv = f2bf(v);
        yhg[idx] = hv;
        ylg[idx] = f2bf(v - __uint_as_float((uint32_t)hv << 16));
      }
    }
}

__global__ __launch_bounds__(256) void k_bucket(const int* __restrict__ idx, int* __restrict__ cnt,
                                                int* __restrict__ lists) {
  int tok = blockIdx.x * 256 + threadIdx.x;
  int e = idx[tok];
  int p = atomicAdd(&cnt[e], 1);
  lists[e * NT + p] = tok;
}

// ---------------- MoE GEMM1: 64 x 128, BK=64, distance-2 reg-prefetch, expert->XCD confinement ----------------
__global__ __launch_bounds__(256) void k_moe1(const uint16_t* __restrict__ xmbf, const uint16_t* __restrict__ w1t,
                                              const float* __restrict__ b1, const int* __restrict__ cnt,
                                              const int* __restrict__ lists, uint16_t* __restrict__ hbf) {
  int bid = blockIdx.x;
  int e = bid & 7;
  int inner = bid >> 3;
  int n0 = (inner & 31) * 128;     // F/128 = 32 n-tiles
  int m0 = (inner >> 5) * 64;      // NT/64 = 64 m-rows
  int c = cnt[e];
  if (m0 >= c) return;
  __shared__ uint16_t As[64][72];
  __shared__ uint16_t Ws[128][72];
  __shared__ int toks[64];
  int tid = threadIdx.x, wv = tid >> 6, ln = tid & 63, mi = ln & 15, b8 = ln >> 4;
  if (tid < 64) toks[tid] = (m0 + tid < c) ? lists[e * NT + m0 + tid] : -1;
  __syncthreads();
  int ra = tid >> 2, ca = (tid & 3) * 16;
  int rw = tid >> 1, cw = (tid & 1) * 32;
  int tk = toks[ra];
  const uint16_t* asrc = (tk >= 0) ? (xmbf + (size_t)tk * D_ + ca) : nullptr;
  const uint16_t* wsrc = w1t + (size_t)e * F_ * D_ + (size_t)(n0 + rw) * D_ + cw;
  f32x4 acc[4][2] = {};
  uint4 a0A = make_uint4(0,0,0,0), a1A = make_uint4(0,0,0,0), w0A, w1A, w2A, w3A;
  uint4 a0B = make_uint4(0,0,0,0), a1B = make_uint4(0,0,0,0), w0B, w1B, w2B, w3B;

#define M1LOAD(S, k0) do {                                                     \
    if (asrc) { a0##S = *(const uint4*)(asrc + (k0)); a1##S = *(const uint4*)(asrc + (k0) + 8); } \
    w0##S = *(const uint4*)(wsrc + (k0));      w1##S = *(const uint4*)(wsrc + (k0) + 8);  \
    w2##S = *(const uint4*)(wsrc + (k0) + 16); w3##S = *(const uint4*)(wsrc + (k0) + 24); \
  } while (0)
#define M1WRITE(S) do {                                                        \
    *(uint4*)&As[ra][ca] = a0##S;       *(uint4*)&As[ra][ca + 8] = a1##S;      \
    *(uint4*)&Ws[rw][cw] = w0##S;       *(uint4*)&Ws[rw][cw + 8] = w1##S;      \
    *(uint4*)&Ws[rw][cw + 16] = w2##S;  *(uint4*)&Ws[rw][cw + 24] = w3##S;     \
  } while (0)
#define M1COMPUTE() do {                                                       \
    _Pragma("unroll")                                                          \
    for (int ks = 0; ks < 2; ks++) {                                           \
      bf16x8 a[4], bb[2];                                                      \
      _Pragma("unroll")                                                        \
      for (int fm = 0; fm < 4; fm++)                                           \
        a[fm] = *(const bf16x8*)&As[fm * 16 + mi][ks * 32 + b8 * 8];           \
      _Pragma("unroll")                                                        \
      for (int nf = 0; nf < 2; nf++)                                           \
        bb[nf] = *(const bf16x8*)&Ws[wv * 32 + nf * 16 + mi][ks * 32 + b8 * 8];\
      _Pragma("unroll")                                                        \
      for (int fm = 0; fm < 4; fm++)                                           \
        _Pragma("unroll")                                                      \
        for (int nf = 0; nf < 2; nf++)                                         \
          acc[fm][nf] = MFMA_BF16(a[fm], bb[nf], acc[fm][nf], 0, 0, 0);        \
    }                                                                          \
  } while (0)

  M1LOAD(A, 0);
  M1WRITE(A);
  M1LOAD(B, 64);
  for (int k0 = 0; k0 < D_; k0 += 128) {
    __syncthreads();
    M1COMPUTE();
    __syncthreads();
    M1WRITE(B);
    if (k0 + 128 < D_) M1LOAD(A, k0 + 128);
    __syncthreads();
    M1COMPUTE();
    __syncthreads();
    if (k0 + 128 < D_) M1WRITE(A);
    if (k0 + 192 < D_) M1LOAD(B, k0 + 192);
  }
#undef M1LOAD
#undef M1WRITE
#undef M1COMPUTE
#pragma unroll
  for (int fm = 0; fm < 4; fm++)
#pragma unroll
    for (int nf = 0; nf < 2; nf++)
#pragma unroll
      for (int rr = 0; rr < 4; rr++) {
        int rt = fm * 16 + b8 * 4 + rr;
        if (m0 + rt < c) {
          int tok = toks[rt];
          int col = n0 + wv * 32 + nf * 16 + mi;
          float v = acc[fm][nf][rr] + b1[e * F_ + col];
          v = v / (1.0f + expf(-v));
          hbf[(size_t)tok * F_ + col] = f2bf(v);
        }
      }
}

// ---------------- MoE GEMM2: 128 x 64 tile (acc[2][4]), BK=64, distance-2 reg-prefetch, XCD confinement ----------------
__global__ __launch_bounds__(256) void k_moe2(const uint16_t* __restrict__ hbf, const uint16_t* __restrict__ w2t,
                                              const float* __restrict__ b2, const float* __restrict__ x2,
                                              const float* __restrict__ sc, const int* __restrict__ cnt,
                                              const int* __restrict__ lists, float* __restrict__ out) {
  int bid = blockIdx.x;
  int e = bid & 7;
  int inner = bid >> 3;
  int n0 = (inner & 15) * 64;       // D/64 = 16 n-tiles
  int m0 = (inner >> 4) * 128;      // NT/128 = 32 m-tiles
  int c = cnt[e];
  if (m0 >= c) return;
  __shared__ uint16_t As[128][72];
  __shared__ uint16_t Ws[64][72];
  __shared__ int toks[128];
  int tid = threadIdx.x, wv = tid >> 6, ln = tid & 63, mi = ln & 15, b8 = ln >> 4;
  if (tid < 128) toks[tid] = (m0 + tid < c) ? lists[e * NT + m0 + tid] : -1;
  __syncthreads();
  int ra = tid >> 1, ca = (tid & 1) * 32;   // A: 2 thr/row, 32 elems each (4 uint4)
  int rw = tid >> 2, cw = (tid & 3) * 16;   // W: 4 thr/row, 16 elems each (2 uint4)
  int tk = toks[ra];
  const uint16_t* asrc = (tk >= 0) ? (hbf + (size_t)tk * F_ + ca) : nullptr;
  const uint16_t* wsrc = w2t + (size_t)e * D_ * F_ + (size_t)(n0 + rw) * F_ + cw;
  f32x4 acc[2][4] = {};
  uint4 a0A = make_uint4(0,0,0,0), a1A = make_uint4(0,0,0,0), a2A = make_uint4(0,0,0,0), a3A = make_uint4(0,0,0,0), w0A, w1A;
  uint4 a0B = make_uint4(0,0,0,0), a1B = make_uint4(0,0,0,0), a2B = make_uint4(0,0,0,0), a3B = make_uint4(0,0,0,0), w0B, w1B;

#define M2LOAD(S, k0) do {                                                     \
    if (asrc) {                                                                \
      a0##S = *(const uint4*)(asrc + (k0));      a1##S = *(const uint4*)(asrc + (k0) + 8);  \
      a2##S = *(const uint4*)(asrc + (k0) + 16); a3##S = *(const uint4*)(asrc + (k0) + 24); \
    }                                                                          \
    w0##S = *(const uint4*)(wsrc + (k0)); w1##S = *(const uint4*)(wsrc + (k0) + 8); \
  } while (0)
#define M2WRITE(S) do {                                                        \
    *(uint4*)&As[ra][ca] = a0##S;       *(uint4*)&As[ra][ca + 8] = a1##S;      \
    *(uint4*)&As[ra][ca + 16] = a2##S;  *(uint4*)&As[ra][ca + 24] = a3##S;     \
    *(uint4*)&Ws[rw][cw] = w0##S;       *(uint4*)&Ws[rw][cw + 8] = w1##S;      \
  } while (0)
#define M2COMPUTE() do {                                                       \
    _Pragma("unroll")                                                          \
    for (int ks = 0; ks < 2; ks++) {                                           \
      bf16x8 a[2], bb[4];                                                      \
      _Pragma("unroll")                                                        \
      for (int fm = 0; fm < 2; fm++)                                           \
        a[fm] = *(const bf16x8*)&As[wv * 32 + fm * 16 + mi][ks * 32 + b8 * 8]; \
      _Pragma("unroll")                                                        \
      for (int fn = 0; fn < 4; fn++)                                           \
        bb[fn] = *(const bf16x8*)&Ws[fn * 16 + mi][ks * 32 + b8 * 8];          \
      _Pragma("unroll")                                                        \
      for (int fm = 0; fm < 2; fm++)                                           \
        _Pragma("unroll")                                                      \
        for (int fn = 0; fn < 4; fn++)                                         \
          acc[fm][fn] = MFMA_BF16(a[fm], bb[fn], acc[fm][fn], 0, 0, 0);        \
    }                                                                          \
  } while (0)

  M2LOAD(A, 0);
  M2WRITE(A);
  M2LOAD(B, 64);
  for (int k0 = 0; k0 < F_; k0 += 128) {
    __syncthreads();
    M2COMPUTE();
    __syncthreads();
    M2WRITE(B);
    if (k0 + 128 < F_) M2LOAD(A, k0 + 128);
    __syncthreads();
    M2COMPUTE();
    __syncthreads();
    if (k0 + 128 < F_) M2WRITE(A);
    if (k0 + 192 < F_) M2LOAD(B, k0 + 192);
  }
#undef M2LOAD
#undef M2WRITE
#undef M2COMPUTE
#pragma unroll
  for (int fm = 0; fm < 2; fm++)
#pragma unroll
    for (int fn = 0; fn < 4; fn++)
#pragma unroll
      for (int rr = 0; rr < 4; rr++) {
        int rt = wv * 32 + fm * 16 + b8 * 4 + rr;
        if (m0 + rt < c) {
          int tok = toks[rt];
          int col = n0 + fn * 16 + mi;
          float v = acc[fm][fn][rr] + b2[e * D_ + col];
          out[(size_t)tok * D_ + col] = x2[(size_t)tok * D_ + col] + sc[tok] * v;
        }
      }
}

extern "C" void kernel_launch(void* const* d_in, const int* in_sizes, int n_in,
                              void* d_out, int out_size, void* d_ws, size_t ws_size,
                              hipStream_t stream) {
  const float* x       = (const float*)d_in[0];
  const float* k_ctx   = (const float*)d_in[1];
  const float* v_ctx   = (const float*)d_in[2];
  const float* sa_nw   = (const float*)d_in[3];
  const float* w_qkv   = (const float*)d_in[4];
  const float* sa_wout = (const float*)d_in[5];
  const float* ca_nw   = (const float*)d_in[6];
  const float* w_q     = (const float*)d_in[7];
  const float* ca_wout = (const float*)d_in[8];
  const float* moe_nw  = (const float*)d_in[9];
  const float* w_gate  = (const float*)d_in[10];
  const float* w1      = (const float*)d_in[11];
  const float* b1      = (const float*)d_in[12];
  const float* w2      = (const float*)d_in[13];
  const float* b2      = (const float*)d_in[14];
  float* out = (float*)d_out;
  (void)in_sizes; (void)n_in; (void)out_size; (void)ws_size;

  char* ws = (char*)d_ws;
  size_t off = 0;
  auto alloc = [&](size_t bytes) { char* p = ws + off; off += (bytes + 255) & ~(size_t)255; return p; };
  uint16_t* xnh   = (uint16_t*)alloc((size_t)NT * D_ * 2);
  uint16_t* xnl   = (uint16_t*)alloc((size_t)NT * D_ * 2);
  uint16_t* yh    = (uint16_t*)alloc((size_t)NT * D_ * 2);
  uint16_t* yl    = (uint16_t*)alloc((size_t)NT * D_ * 2);
  float*    x1    = (float*)alloc((size_t)NT * D_ * 4);
  uint16_t* qkvh  = (uint16_t*)alloc((size_t)NT * 3 * D_ * 2);   // 24 MB
  uint16_t* qkvl  = (uint16_t*)alloc((size_t)NT * 3 * D_ * 2);   // 24 MB
  float* x2 = (float*)qkvh;
  uint16_t* qch = qkvl;
  uint16_t* qcl = qkvl + (size_t)NT * D_;
  uint16_t* wqkvTh = (uint16_t*)alloc((size_t)D_ * 3 * D_ * 2);
  uint16_t* wqkvTl = (uint16_t*)alloc((size_t)D_ * 3 * D_ * 2);
  uint16_t* sawTh  = (uint16_t*)alloc((size_t)D_ * D_ * 2);
  uint16_t* sawTl  = (uint16_t*)alloc((size_t)D_ * D_ * 2);
  uint16_t* wqTh   = (uint16_t*)alloc((size_t)D_ * D_ * 2);
  uint16_t* wqTl   = (uint16_t*)alloc((size_t)D_ * D_ * 2);
  uint16_t* cawTh  = (uint16_t*)alloc((size_t)D_ * D_ * 2);
  uint16_t* cawTl  = (uint16_t*)alloc((size_t)D_ * D_ * 2);
  uint16_t* w1t   = (uint16_t*)alloc((size_t)E_ * D_ * F_ * 2);
  uint16_t* w2t   = (uint16_t*)alloc((size_t)E_ * D_ * F_ * 2);
  uint16_t* hbf   = (uint16_t*)alloc((size_t)NT * F_ * 2);   // 32 MB, MoE-phase only
  uint16_t* vth   = (uint16_t*)hbf;                                        // 8 MB
  uint16_t* vtl   = vth + (size_t)NT * D_;                                 // 8 MB
  uint16_t* kch   = (uint16_t*)((char*)hbf + (size_t)16 * 1024 * 1024);    // 2 MB
  uint16_t* kcl   = (uint16_t*)((char*)hbf + (size_t)18 * 1024 * 1024);    // 2 MB
  uint16_t* vcth  = (uint16_t*)((char*)hbf + (size_t)20 * 1024 * 1024);    // 2 MB
  uint16_t* vctl  = (uint16_t*)((char*)hbf + (size_t)22 * 1024 * 1024);    // 2 MB
  uint16_t* xmbf  = (uint16_t*)alloc((size_t)NT * D_ * 2);
  int*   idx   = (int*)alloc(NT * 4);
  float* scb   = (float*)alloc(NT * 4);
  int*   cnt   = (int*)alloc(256);
  int*   lists = (int*)alloc((size_t)E_ * NT * 4);

  // weight prep (merged launches)
  k_pack_all<<<dim3(16, 16, 6), 256, 0, stream>>>(w_qkv, sa_wout, w_q, ca_wout,
                                                  wqkvTh, wqkvTl, sawTh, sawTl,
                                                  wqTh, wqTl, cawTh, cawTl);
  k_bf_t2<<<dim3(1024, 1, 16), 256, 0, stream>>>(w1, w2, w1t, w2t);
  // cross-attn K/V prep (planes)
  k_packf2<<<(B_ * T_ * 256) / 1024, 256, 0, stream>>>(k_ctx, kch, kcl);
  k_tf32<<<dim3(T_ / 32, 256 / 32, B_), 256, 0, stream>>>(v_ctx, vcth, vctl);

  // self-attention block
  k_rms<<<NT, 256, 0, stream>>>(x, sa_nw, xnh, xnl, nullptr, nullptr, nullptr);
  k_gemm_split<<<dim3(3 * D_ / GBN, NT / GBM), 256, 0, stream>>>(xnh, xnl, wqkvTh, wqkvTl, nullptr, nullptr, qkvh, qkvl, 1024, NT, 3 * D_, D_);
  k_t16<<<dim3(T_ / 64, D_ / 64, B_), 256, 0, stream>>>(qkvh, qkvl, vth, vtl);
  k_fattn<true><<<dim3(T_ / 128, H_, B_), 256, 0, stream>>>(qkvh, qkvl, 3072, qkvh + 1024, qkvl + 1024, 3072, 1, vth, vtl, 1024, yh, yl);
  k_gemm_split<<<dim3(D_ / GBN, NT / GBM), 256, 0, stream>>>(yh, yl, sawTh, sawTl, x1, x, nullptr, nullptr, 0, NT, D_, D_);

  // cross-attention block (GQA)
  k_rms<<<NT, 256, 0, stream>>>(x1, ca_nw, xnh, xnl, nullptr, nullptr, nullptr);
  k_gemm_split<<<dim3(D_ / GBN, NT / GBM), 256, 0, stream>>>(xnh, xnl, wqTh, wqTl, nullptr, nullptr, qch, qcl, 1024, NT, D_, D_);
  k_fattn<false><<<dim3(T_ / 128, H_, B_), 256, 0, stream>>>(qch, qcl, 1024, kch, kcl, 256, 4, vcth, vctl, 256, yh, yl);
  k_gemm_split<<<dim3(D_ / GBN, NT / GBM), 256, 0, stream>>>(yh, yl, cawTh, cawTl, x2, x1, nullptr, nullptr, 0, NT, D_, D_);

  // MoE (gate fused into RMSNorm); expert->XCD confined 1D grids
  k_rms<<<NT, 256, 0, stream>>>(x2, moe_nw, xmbf, nullptr, w_gate, idx, scb);
  hipMemsetAsync(cnt, 0, 32, stream);
  k_bucket<<<NT / 256, 256, 0, stream>>>(idx, cnt, lists);
  k_moe1<<<dim3(8 * (F_ / 128) * (NT / 64)), 256, 0, stream>>>(xmbf, w1t, b1, cnt, lists, hbf);
  k_moe2<<<dim3(8 * (D_ / 64) * (NT / 128)), 256, 0, stream>>>(hbf, w2t, b2, x2, scb, cnt, lists, out);
}